// Round 1
// baseline (527.008 us; speedup 1.0000x reference)
//
#include <hip/hip_runtime.h>
#include <hip/hip_bf16.h>

// ---------------------------------------------------------------------------
// Transformer block: LN1 -> QKV -> MHA(16 heads, Hd=64, N=1024) -> proj+res
//                    -> LN2 -> FFN(4096, exact gelu) + res
// B=8, N=1024, D=1024 -> 8192 tokens. All GEMMs in bf16 MFMA, f32 accum.
// ---------------------------------------------------------------------------

typedef float f32x4 __attribute__((ext_vector_type(4)));
typedef short bf16x8 __attribute__((ext_vector_type(8)));

#define DEV __device__ __forceinline__

DEV f32x4 mfma16(bf16x8 a, bf16x8 b, f32x4 c) {
    return __builtin_amdgcn_mfma_f32_16x16x32_bf16(a, b, c, 0, 0, 0);
}

DEV ushort f2bf(float f) {  // round-to-nearest-even f32 -> bf16
    union { float f; unsigned u; } v; v.f = f;
    unsigned r = v.u + 0x7FFFu + ((v.u >> 16) & 1u);
    return (ushort)(r >> 16);
}

DEV void gload_lds16(const void* g, void* l) {
    __builtin_amdgcn_global_load_lds(
        (const __attribute__((address_space(1))) void*)g,
        (__attribute__((address_space(3))) void*)l, 16, 0, 0);
}

// ---------------------------------------------------------------------------
// Weight transpose + cast: src [K][N] f32 -> dst [N][K] bf16
// ---------------------------------------------------------------------------
__global__ __launch_bounds__(256) void transpose_w(
    const float* __restrict__ src, ushort* __restrict__ dst, int K, int N)
{
    __shared__ float tile[32][33];
    const int n0 = blockIdx.x * 32, k0 = blockIdx.y * 32;
    const int tx = threadIdx.x, ty = threadIdx.y;
#pragma unroll
    for (int i = 0; i < 32; i += 8)
        tile[ty + i][tx] = src[(size_t)(k0 + ty + i) * N + n0 + tx];
    __syncthreads();
#pragma unroll
    for (int i = 0; i < 32; i += 8)
        dst[(size_t)(n0 + ty + i) * K + k0 + tx] = f2bf(tile[tx][ty + i]);
}

// ---------------------------------------------------------------------------
// LayerNorm (D=1024): one block per row, f32 in -> bf16 out
// ---------------------------------------------------------------------------
__global__ __launch_bounds__(256) void ln_bf16(
    const float* __restrict__ x, const float* __restrict__ gw,
    const float* __restrict__ bw, ushort* __restrict__ out)
{
    const int row = blockIdx.x;
    const int t = threadIdx.x;
    const float4 v = ((const float4*)(x + (size_t)row * 1024))[t];
    float s  = v.x + v.y + v.z + v.w;
    float s2 = v.x * v.x + v.y * v.y + v.z * v.z + v.w * v.w;
#pragma unroll
    for (int off = 32; off; off >>= 1) {
        s  += __shfl_xor(s, off);
        s2 += __shfl_xor(s2, off);
    }
    __shared__ float red[16];
    const int wave = t >> 6, lane = t & 63;
    if (lane == 0) { red[wave] = s; red[8 + wave] = s2; }
    __syncthreads();
    s  = red[0] + red[1] + red[2] + red[3];
    s2 = red[8] + red[9] + red[10] + red[11];
    const float mean = s * (1.0f / 1024.0f);
    const float var  = s2 * (1.0f / 1024.0f) - mean * mean;
    const float rstd = rsqrtf(var + 1e-5f);
    const float4 gv = ((const float4*)gw)[t];
    const float4 bv = ((const float4*)bw)[t];
    ushort4 o;
    o.x = f2bf((v.x - mean) * rstd * gv.x + bv.x);
    o.y = f2bf((v.y - mean) * rstd * gv.y + bv.y);
    o.z = f2bf((v.z - mean) * rstd * gv.z + bv.z);
    o.w = f2bf((v.w - mean) * rstd * gv.w + bv.w);
    ((ushort4*)out)[(size_t)row * 256 + t] = o;
}

// ---------------------------------------------------------------------------
// GEMM: C[M,N] = A[M,K](bf16) @ BT[N,K]^T(bf16) + bias, m97 structure:
// 128x128 tile, BK=32, 4 waves (2x2), 4x4 16x16x32 MFMA frags per wave.
// EPI: 0 = bf16 out (bias), 1 = f32 out (bias + residual), 2 = bf16 gelu(bias)
// ---------------------------------------------------------------------------
template <int EPI>
__global__ __launch_bounds__(256) void gemm_bt(
    const ushort* __restrict__ A, const ushort* __restrict__ BT,
    const float* __restrict__ bias, const float* __restrict__ res,
    void* __restrict__ out, int M, int N, int K)
{
    __shared__ __align__(16) ushort As[128 * 32];
    __shared__ __align__(16) ushort Bs[128 * 32];

    const int tid = threadIdx.x;
    const int wave = tid >> 6, lane = tid & 63;
    const int g = lane >> 4, lr = lane & 15;
    const int wr = wave >> 1, wc = wave & 1;
    const int m0 = blockIdx.y * 128, n0 = blockIdx.x * 128;

    f32x4 acc[4][4] = {};

    // staging: chunk c (of 8) = 16 rows; lane covers row c*16+(l>>2), k (l&3)*8
    const int srow = lane >> 2, skk = (lane & 3) * 8;
    const ushort* ag0 = A  + (size_t)(m0 + wave * 16      + srow) * K + skk;
    const ushort* ag1 = A  + (size_t)(m0 + (wave + 4) * 16 + srow) * K + skk;
    const ushort* bg0 = BT + (size_t)(n0 + wave * 16      + srow) * K + skk;
    const ushort* bg1 = BT + (size_t)(n0 + (wave + 4) * 16 + srow) * K + skk;
    ushort* as0 = As + wave * 512;       ushort* as1 = As + (wave + 4) * 512;
    ushort* bs0 = Bs + wave * 512;       ushort* bs1 = Bs + (wave + 4) * 512;

    for (int kt = 0; kt < K; kt += 32) {
        gload_lds16(ag0 + kt, as0);
        gload_lds16(ag1 + kt, as1);
        gload_lds16(bg0 + kt, bs0);
        gload_lds16(bg1 + kt, bs1);
        __syncthreads();
        bf16x8 af[4], bfv[4];
#pragma unroll
        for (int m = 0; m < 4; ++m)
            af[m] = *(const bf16x8*)(As + (wr * 64 + m * 16 + lr) * 32 + g * 8);
#pragma unroll
        for (int n = 0; n < 4; ++n)
            bfv[n] = *(const bf16x8*)(Bs + (wc * 64 + n * 16 + lr) * 32 + g * 8);
#pragma unroll
        for (int m = 0; m < 4; ++m)
#pragma unroll
            for (int n = 0; n < 4; ++n)
                acc[m][n] = mfma16(af[m], bfv[n], acc[m][n]);
        __syncthreads();
    }

    // epilogue: C/D layout col = lr, row = 4*g + r
#pragma unroll
    for (int n = 0; n < 4; ++n) {
        const int col = n0 + wc * 64 + n * 16 + lr;
        const float bv = bias[col];
#pragma unroll
        for (int m = 0; m < 4; ++m) {
            const int row0 = m0 + wr * 64 + m * 16 + 4 * g;
#pragma unroll
            for (int r = 0; r < 4; ++r) {
                float v = acc[m][n][r] + bv;
                const size_t idx = (size_t)(row0 + r) * N + col;
                if constexpr (EPI == 1) {
                    ((float*)out)[idx] = v + res[idx];
                } else if constexpr (EPI == 2) {
                    v = 0.5f * v * (1.0f + erff(v * 0.70710678118654752f));
                    ((ushort*)out)[idx] = f2bf(v);
                } else {
                    ((ushort*)out)[idx] = f2bf(v);
                }
            }
        }
    }
}

// ---------------------------------------------------------------------------
// Flash attention: grid (16 qtiles, 128 b*h), block 256 (4 waves).
// Q tile 64 rows (16/wave, in regs), K/V tiles 64 keys.
// qkv layout: [b*1024+n][3072] with q at col h*64, k at 1024+h*64, v at 2048+h*64
// K staged in LDS with XOR swizzle; V staged transposed [d][n'] with swizzle.
// ---------------------------------------------------------------------------
__global__ __launch_bounds__(256) void attn_kernel(
    const ushort* __restrict__ qkv, ushort* __restrict__ o)
{
    __shared__ __align__(16) ushort Ks[64 * 64];
    __shared__ __align__(16) ushort Vt[64 * 64];
    __shared__ __align__(16) ushort Ps[4][16 * 72];

    const int tid = threadIdx.x;
    const int wave = tid >> 6, lane = tid & 63;
    const int g = lane >> 4, lr = lane & 15;
    const int b = blockIdx.y >> 4, h = blockIdx.y & 15;
    const int q0 = blockIdx.x * 64;

    const size_t base = (size_t)b * 1024 * 3072;

    // Q fragments (A-operand), hoisted: row = lr of this wave's 16-row stripe
    const ushort* qp = qkv + base + (size_t)(q0 + wave * 16 + lr) * 3072 + h * 64;
    const bf16x8 qf0 = *(const bf16x8*)(qp + g * 8);
    const bf16x8 qf1 = *(const bf16x8*)(qp + 32 + g * 8);

    float mrow[4], lrow[4];
    f32x4 oacc[4] = {};
#pragma unroll
    for (int r = 0; r < 4; ++r) { mrow[r] = -1e30f; lrow[r] = 0.f; }

    for (int kt = 0; kt < 16; ++kt) {
        const int n0 = kt * 64;
        __syncthreads();   // previous iter's LDS reads complete
#pragma unroll
        for (int i = 0; i < 2; ++i) {
            const int c = tid + i * 256;
            const int r = c >> 3, dc = c & 7;
            const ushort* kg = qkv + base + (size_t)(n0 + r) * 3072 + 1024 + h * 64 + dc * 8;
            const bf16x8 kv = *(const bf16x8*)kg;
            *(bf16x8*)(Ks + r * 64 + ((dc ^ (r & 7)) << 3)) = kv;
            const ushort* vg = qkv + base + (size_t)(n0 + r) * 3072 + 2048 + h * 64 + dc * 8;
            const bf16x8 vv = *(const bf16x8*)vg;
#pragma unroll
            for (int j = 0; j < 8; ++j) {
                const int d = dc * 8 + j;
                Vt[d * 64 + (((r >> 3) ^ (d & 7)) << 3) + (r & 7)] = (ushort)vv[j];
            }
        }
        __syncthreads();

        // S = Q K^T  (B-frag: col = key c*16+lr, k = d)
        f32x4 sacc[4];
#pragma unroll
        for (int c = 0; c < 4; ++c) {
            f32x4 a = {0.f, 0.f, 0.f, 0.f};
            const int row = c * 16 + lr;
            a = mfma16(qf0, *(const bf16x8*)(Ks + row * 64 + ((g       ^ (lr & 7)) << 3)), a);
            a = mfma16(qf1, *(const bf16x8*)(Ks + row * 64 + (((4 + g) ^ (lr & 7)) << 3)), a);
            sacc[c] = a;
        }
#pragma unroll
        for (int c = 0; c < 4; ++c) sacc[c] *= 0.125f;  // Hd^-0.5

        // online softmax: lane holds rows 4g+r, cols c*16+lr; reduce over lr
        float mnew[4], resc[4], psum[4];
#pragma unroll
        for (int r = 0; r < 4; ++r) {
            float mx = fmaxf(fmaxf(sacc[0][r], sacc[1][r]),
                             fmaxf(sacc[2][r], sacc[3][r]));
#pragma unroll
            for (int off = 1; off < 16; off <<= 1) mx = fmaxf(mx, __shfl_xor(mx, off));
            mnew[r] = fmaxf(mrow[r], mx);
            resc[r] = __expf(mrow[r] - mnew[r]);
            mrow[r] = mnew[r];
            psum[r] = 0.f;
        }
        ushort* pw = Ps[wave];
#pragma unroll
        for (int c = 0; c < 4; ++c)
#pragma unroll
            for (int r = 0; r < 4; ++r) {
                const float p = __expf(sacc[c][r] - mnew[r]);
                psum[r] += p;
                pw[(4 * g + r) * 72 + c * 16 + lr] = f2bf(p);
            }
#pragma unroll
        for (int r = 0; r < 4; ++r) {
            float ps = psum[r];
#pragma unroll
            for (int off = 1; off < 16; off <<= 1) ps += __shfl_xor(ps, off);
            lrow[r] = lrow[r] * resc[r] + ps;
        }
#pragma unroll
        for (int c = 0; c < 4; ++c)
#pragma unroll
            for (int r = 0; r < 4; ++r) oacc[c][r] *= resc[r];

        // O += P V   (A-frag from per-wave P rows; B-frag from Vt rows = d)
#pragma unroll
        for (int s = 0; s < 2; ++s) {
            const bf16x8 pf = *(const bf16x8*)(pw + lr * 72 + s * 32 + g * 8);
#pragma unroll
            for (int c = 0; c < 4; ++c) {
                const int d = c * 16 + lr;
                const bf16x8 vf = *(const bf16x8*)(Vt + d * 64 + (((4 * s + g) ^ (d & 7)) << 3));
                oacc[c] = mfma16(pf, vf, oacc[c]);
            }
        }
    }

#pragma unroll
    for (int r = 0; r < 4; ++r) {
        const float inv = 1.0f / lrow[r];
        const size_t orow = (size_t)(b * 1024 + q0 + wave * 16 + 4 * g + r) * 1024 + h * 64;
#pragma unroll
        for (int c = 0; c < 4; ++c)
            o[orow + c * 16 + lr] = f2bf(oacc[c][r] * inv);
    }
}

// ---------------------------------------------------------------------------
extern "C" void kernel_launch(void* const* d_in, const int* in_sizes, int n_in,
                              void* d_out, int out_size, void* d_ws, size_t ws_size,
                              hipStream_t stream)
{
    const float* x      = (const float*)d_in[0];
    const float* qkv_w  = (const float*)d_in[1];
    const float* qkv_b  = (const float*)d_in[2];
    const float* out_w  = (const float*)d_in[3];
    const float* out_b  = (const float*)d_in[4];
    const float* ffn_w1 = (const float*)d_in[5];
    const float* ffn_b1 = (const float*)d_in[6];
    const float* ffn_w2 = (const float*)d_in[7];
    const float* ffn_b2 = (const float*)d_in[8];
    const float* ln1_g  = (const float*)d_in[9];
    const float* ln1_b  = (const float*)d_in[10];
    const float* ln2_g  = (const float*)d_in[11];
    const float* ln2_b  = (const float*)d_in[12];

    constexpr size_t MB = 1u << 20;
    char* ws = (char*)d_ws;
    ushort* wt_qkv = (ushort*)(ws + 0 * MB);     // [3072][1024] bf16  (6 MB)
    ushort* wt_out = (ushort*)(ws + 6 * MB);     // [1024][1024]       (2 MB)
    ushort* wt_f1  = (ushort*)(ws + 8 * MB);     // [4096][1024]       (8 MB)
    ushort* wt_f2  = (ushort*)(ws + 16 * MB);    // [1024][4096]       (8 MB)
    float*  x1     = (float*) (ws + 24 * MB);    // [8192][1024] f32   (32 MB)
    ushort* hbuf   = (ushort*)(ws + 56 * MB);    // [8192][1024] bf16  (16 MB)
    ushort* qkvb   = (ushort*)(ws + 72 * MB);    // [8192][3072] bf16  (48 MB)
    ushort* obuf   = (ushort*)(ws + 120 * MB);   // [8192][1024] bf16  (16 MB)
    ushort* gbuf   = (ushort*)(ws + 72 * MB);    // [8192][4096] bf16  (64 MB, aliases qkvb+obuf)

    const dim3 tb(32, 8);
    transpose_w<<<dim3(3072 / 32, 1024 / 32), tb, 0, stream>>>(qkv_w,  wt_qkv, 1024, 3072);
    transpose_w<<<dim3(1024 / 32, 1024 / 32), tb, 0, stream>>>(out_w,  wt_out, 1024, 1024);
    transpose_w<<<dim3(4096 / 32, 1024 / 32), tb, 0, stream>>>(ffn_w1, wt_f1,  1024, 4096);
    transpose_w<<<dim3(1024 / 32, 4096 / 32), tb, 0, stream>>>(ffn_w2, wt_f2,  4096, 1024);

    ln_bf16<<<8192, 256, 0, stream>>>(x, ln1_g, ln1_b, hbuf);

    gemm_bt<0><<<dim3(3072 / 128, 8192 / 128), 256, 0, stream>>>(
        hbuf, wt_qkv, qkv_b, nullptr, qkvb, 8192, 3072, 1024);

    attn_kernel<<<dim3(16, 128), 256, 0, stream>>>(qkvb, obuf);

    gemm_bt<1><<<dim3(1024 / 128, 8192 / 128), 256, 0, stream>>>(
        obuf, wt_out, out_b, x, x1, 8192, 1024, 1024);

    ln_bf16<<<8192, 256, 0, stream>>>(x1, ln2_g, ln2_b, hbuf);

    gemm_bt<2><<<dim3(4096 / 128, 8192 / 128), 256, 0, stream>>>(
        hbuf, wt_f1, ffn_b1, nullptr, gbuf, 8192, 4096, 1024);

    gemm_bt<1><<<dim3(1024 / 128, 8192 / 128), 256, 0, stream>>>(
        gbuf, wt_f2, ffn_b2, x1, (float*)d_out, 8192, 1024, 4096);
}

// Round 3
// 475.446 us; speedup vs baseline: 1.1084x; 1.1084x over previous
//
#include <hip/hip_runtime.h>
#include <hip/hip_bf16.h>

// ---------------------------------------------------------------------------
// Transformer block: LN1 -> QKV -> MHA(16 heads, Hd=64, N=1024) -> proj+res
//                    -> LN2 -> FFN(4096, exact gelu) + res
// B=8, N=1024, D=1024 -> 8192 tokens. All GEMMs in bf16 MFMA, f32 accum.
// ---------------------------------------------------------------------------

typedef float f32x4 __attribute__((ext_vector_type(4)));
typedef short bf16x8 __attribute__((ext_vector_type(8)));

#define DEV __device__ __forceinline__

DEV f32x4 mfma16(bf16x8 a, bf16x8 b, f32x4 c) {
    return __builtin_amdgcn_mfma_f32_16x16x32_bf16(a, b, c, 0, 0, 0);
}

DEV ushort f2bf(float f) {  // round-to-nearest-even f32 -> bf16
    union { float f; unsigned u; } v; v.f = f;
    unsigned r = v.u + 0x7FFFu + ((v.u >> 16) & 1u);
    return (ushort)(r >> 16);
}

DEV void gload_lds16(const void* g, void* l) {
    __builtin_amdgcn_global_load_lds(
        (const __attribute__((address_space(1))) void*)g,
        (__attribute__((address_space(3))) void*)l, 16, 0, 0);
}

// ---------------------------------------------------------------------------
// Weight transpose + cast: src [K][N] f32 -> dst [N][K] bf16
// ---------------------------------------------------------------------------
__global__ __launch_bounds__(256) void transpose_w(
    const float* __restrict__ src, ushort* __restrict__ dst, int K, int N)
{
    __shared__ float tile[32][33];
    const int n0 = blockIdx.x * 32, k0 = blockIdx.y * 32;
    const int tx = threadIdx.x, ty = threadIdx.y;
#pragma unroll
    for (int i = 0; i < 32; i += 8)
        tile[ty + i][tx] = src[(size_t)(k0 + ty + i) * N + n0 + tx];
    __syncthreads();
#pragma unroll
    for (int i = 0; i < 32; i += 8)
        dst[(size_t)(n0 + ty + i) * K + k0 + tx] = f2bf(tile[tx][ty + i]);
}

// ---------------------------------------------------------------------------
// V transpose: qkvb [b*1024+n][3072] (v at col 2048+h*64+d) -> vt[b][h][d][n]
// ---------------------------------------------------------------------------
__global__ __launch_bounds__(256) void transpose_v(
    const ushort* __restrict__ qkvb, ushort* __restrict__ vt)
{
    __shared__ ushort tile[32][33];
    const int b = blockIdx.z >> 4, h = blockIdx.z & 15;
    const int n0 = blockIdx.x * 32, d0 = blockIdx.y * 32;
    const int tx = threadIdx.x, ty = threadIdx.y;
#pragma unroll
    for (int i = 0; i < 32; i += 8)
        tile[ty + i][tx] =
            qkvb[(size_t)(b * 1024 + n0 + ty + i) * 3072 + 2048 + h * 64 + d0 + tx];
    __syncthreads();
#pragma unroll
    for (int i = 0; i < 32; i += 8)
        vt[((size_t)(b * 16 + h) * 64 + d0 + ty + i) * 1024 + n0 + tx] = tile[tx][ty + i];
}

// ---------------------------------------------------------------------------
// LayerNorm (D=1024): one block per row, f32 in -> bf16 out
// ---------------------------------------------------------------------------
__global__ __launch_bounds__(256) void ln_bf16(
    const float* __restrict__ x, const float* __restrict__ gw,
    const float* __restrict__ bw, ushort* __restrict__ out)
{
    const int row = blockIdx.x;
    const int t = threadIdx.x;
    const float4 v = ((const float4*)(x + (size_t)row * 1024))[t];
    float s  = v.x + v.y + v.z + v.w;
    float s2 = v.x * v.x + v.y * v.y + v.z * v.z + v.w * v.w;
#pragma unroll
    for (int off = 32; off; off >>= 1) {
        s  += __shfl_xor(s, off);
        s2 += __shfl_xor(s2, off);
    }
    __shared__ float red[16];
    const int wave = t >> 6, lane = t & 63;
    if (lane == 0) { red[wave] = s; red[8 + wave] = s2; }
    __syncthreads();
    s  = red[0] + red[1] + red[2] + red[3];
    s2 = red[8] + red[9] + red[10] + red[11];
    const float mean = s * (1.0f / 1024.0f);
    const float var  = s2 * (1.0f / 1024.0f) - mean * mean;
    const float rstd = rsqrtf(var + 1e-5f);
    const float4 gv = ((const float4*)gw)[t];
    const float4 bv = ((const float4*)bw)[t];
    ushort4 o;
    o.x = f2bf((v.x - mean) * rstd * gv.x + bv.x);
    o.y = f2bf((v.y - mean) * rstd * gv.y + bv.y);
    o.z = f2bf((v.z - mean) * rstd * gv.z + bv.z);
    o.w = f2bf((v.w - mean) * rstd * gv.w + bv.w);
    ((ushort4*)out)[(size_t)row * 256 + t] = o;
}

// ---------------------------------------------------------------------------
// GEMM: C[M,N] = A[M,K](bf16) @ BT[N,K]^T(bf16) + bias, m97 structure:
// 128x128 tile, BK=32, 4 waves (2x2), 4x4 16x16x32 MFMA frags per wave.
// XCD-aware block swizzle (nwg % 8 == 0 for all our grids).
// EPI: 0 = bf16 out (bias), 1 = f32 out (bias + residual), 2 = bf16 gelu(bias)
// ---------------------------------------------------------------------------
template <int EPI>
__global__ __launch_bounds__(256) void gemm_bt(
    const ushort* __restrict__ A, const ushort* __restrict__ BT,
    const float* __restrict__ bias, const float* __restrict__ res,
    void* __restrict__ out, int M, int N, int K)
{
    __shared__ __align__(16) ushort As[128 * 32];
    __shared__ __align__(16) ushort Bs[128 * 32];

    const int tid = threadIdx.x;
    const int wave = tid >> 6, lane = tid & 63;
    const int g = lane >> 4, lr = lane & 15;
    const int wr = wave >> 1, wc = wave & 1;

    // XCD swizzle: dispatch d lands on XCD d%8; give each XCD a contiguous chunk
    const int gx = gridDim.x;
    const int nwg = gx * gridDim.y;
    int id = blockIdx.y * gx + blockIdx.x;
    id = (id & 7) * (nwg >> 3) + (id >> 3);
    const int m0 = (id / gx) * 128, n0 = (id % gx) * 128;

    f32x4 acc[4][4] = {};

    // staging: chunk c (of 8) = 16 rows; lane covers row c*16+(l>>2), k (l&3)*8
    const int srow = lane >> 2, skk = (lane & 3) * 8;
    const ushort* ag0 = A  + (size_t)(m0 + wave * 16      + srow) * K + skk;
    const ushort* ag1 = A  + (size_t)(m0 + (wave + 4) * 16 + srow) * K + skk;
    const ushort* bg0 = BT + (size_t)(n0 + wave * 16      + srow) * K + skk;
    const ushort* bg1 = BT + (size_t)(n0 + (wave + 4) * 16 + srow) * K + skk;
    ushort* as0 = As + wave * 512;       ushort* as1 = As + (wave + 4) * 512;
    ushort* bs0 = Bs + wave * 512;       ushort* bs1 = Bs + (wave + 4) * 512;

    for (int kt = 0; kt < K; kt += 32) {
        gload_lds16(ag0 + kt, as0);
        gload_lds16(ag1 + kt, as1);
        gload_lds16(bg0 + kt, bs0);
        gload_lds16(bg1 + kt, bs1);
        __syncthreads();
        bf16x8 af[4], bfv[4];
#pragma unroll
        for (int m = 0; m < 4; ++m)
            af[m] = *(const bf16x8*)(As + (wr * 64 + m * 16 + lr) * 32 + g * 8);
#pragma unroll
        for (int n = 0; n < 4; ++n)
            bfv[n] = *(const bf16x8*)(Bs + (wc * 64 + n * 16 + lr) * 32 + g * 8);
#pragma unroll
        for (int m = 0; m < 4; ++m)
#pragma unroll
            for (int n = 0; n < 4; ++n)
                acc[m][n] = mfma16(af[m], bfv[n], acc[m][n]);
        __syncthreads();
    }

    // epilogue: C/D layout col = lr, row = 4*g + r
#pragma unroll
    for (int n = 0; n < 4; ++n) {
        const int col = n0 + wc * 64 + n * 16 + lr;
        const float bv = bias[col];
#pragma unroll
        for (int m = 0; m < 4; ++m) {
            const int row0 = m0 + wr * 64 + m * 16 + 4 * g;
#pragma unroll
            for (int r = 0; r < 4; ++r) {
                float v = acc[m][n][r] + bv;
                const size_t idx = (size_t)(row0 + r) * N + col;
                if constexpr (EPI == 1) {
                    ((float*)out)[idx] = v + res[idx];
                } else if constexpr (EPI == 2) {
                    v = 0.5f * v * (1.0f + erff(v * 0.70710678118654752f));
                    ((ushort*)out)[idx] = f2bf(v);
                } else {
                    ((ushort*)out)[idx] = f2bf(v);
                }
            }
        }
    }
}

// ---------------------------------------------------------------------------
// Flash attention: 2048 blocks (16 qtiles x 128 b*h), block 256 (4 waves).
// Q tile 64 rows (16/wave, in regs), K/V tiles 64 keys.
// K from qkv rows; V from pre-transposed vt[b][h][d][n]. Each thread stages
// TWO rows (sr and sr+32) per tile with vectorized bf16x8 swizzled writes.
// XCD swizzle groups all 16 q-tiles of one (b,h) onto one XCD for K/V L2 reuse.
// ---------------------------------------------------------------------------
__global__ __launch_bounds__(256) void attn_kernel(
    const ushort* __restrict__ qkv, const ushort* __restrict__ vtb,
    ushort* __restrict__ o)
{
    __shared__ __align__(16) ushort Ks[64 * 64];
    __shared__ __align__(16) ushort Vt[64 * 64];
    __shared__ __align__(16) ushort Ps[4][16 * 72];

    const int tid = threadIdx.x;
    const int wave = tid >> 6, lane = tid & 63;
    const int g = lane >> 4, lr = lane & 15;

    // XCD-aware remap (nwg=2048): logical id: qt fast, bh slow
    const int hwid = blockIdx.y * 16 + blockIdx.x;
    const int logical = (hwid & 7) * 256 + (hwid >> 3);
    const int qt = logical & 15, bh = logical >> 4;
    const int b = bh >> 4, h = bh & 15;
    const int q0 = qt * 64;

    const size_t base  = (size_t)b * 1024 * 3072;
    const size_t vbase = (size_t)bh * 64 * 1024;

    // Q fragments (A-operand), hoisted: row = lr of this wave's 16-row stripe
    const ushort* qp = qkv + base + (size_t)(q0 + wave * 16 + lr) * 3072 + h * 64;
    const bf16x8 qf0 = *(const bf16x8*)(qp + g * 8);
    const bf16x8 qf1 = *(const bf16x8*)(qp + 32 + g * 8);

    // staging: thread covers rows sr and sr+32 (0..63), 16B col-block sc (0..7)
    // (sr+32)&7 == sr&7 so the swizzle key is identical for both rows.
    const int sr = tid >> 3, sc = tid & 7;
    const int swz = (sc ^ (sr & 7)) << 3;
    const ushort* kg0 = qkv + base + (size_t)sr * 3072 + 1024 + h * 64 + sc * 8;
    const ushort* kg1 = kg0 + (size_t)32 * 3072;
    const ushort* vg0 = vtb + vbase + (size_t)sr * 1024 + sc * 8;
    const ushort* vg1 = vg0 + (size_t)32 * 1024;
    ushort* ksw0 = Ks + sr * 64 + swz;
    ushort* ksw1 = Ks + (sr + 32) * 64 + swz;
    ushort* vsw0 = Vt + sr * 64 + swz;
    ushort* vsw1 = Vt + (sr + 32) * 64 + swz;

    float mrow[4], lrow[4];
    f32x4 oacc[4] = {};
#pragma unroll
    for (int r = 0; r < 4; ++r) { mrow[r] = -1e30f; lrow[r] = 0.f; }

    constexpr float SCL = 0.18033688011112042f;  // Hd^-0.5 * log2(e)

    for (int kt = 0; kt < 16; ++kt) {
        const int n0 = kt * 64;
        __syncthreads();   // previous iter's LDS reads complete
        *(bf16x8*)ksw0 = *(const bf16x8*)(kg0 + (size_t)n0 * 3072);
        *(bf16x8*)ksw1 = *(const bf16x8*)(kg1 + (size_t)n0 * 3072);
        *(bf16x8*)vsw0 = *(const bf16x8*)(vg0 + n0);
        *(bf16x8*)vsw1 = *(const bf16x8*)(vg1 + n0);
        __syncthreads();

        // S = Q K^T  (B-frag: col = key c*16+lr, k = d)
        f32x4 sacc[4];
#pragma unroll
        for (int c = 0; c < 4; ++c) {
            f32x4 a = {0.f, 0.f, 0.f, 0.f};
            const int row = c * 16 + lr;
            a = mfma16(qf0, *(const bf16x8*)(Ks + row * 64 + ((g       ^ (lr & 7)) << 3)), a);
            a = mfma16(qf1, *(const bf16x8*)(Ks + row * 64 + (((4 + g) ^ (lr & 7)) << 3)), a);
            sacc[c] = a;
        }
#pragma unroll
        for (int c = 0; c < 4; ++c) sacc[c] *= SCL;  // log2-domain scores

        // online softmax (base 2): lane holds rows 4g+r, cols c*16+lr
        float mnew[4], resc[4], psum[4];
#pragma unroll
        for (int r = 0; r < 4; ++r) {
            float mx = fmaxf(fmaxf(sacc[0][r], sacc[1][r]),
                             fmaxf(sacc[2][r], sacc[3][r]));
#pragma unroll
            for (int off = 1; off < 16; off <<= 1) mx = fmaxf(mx, __shfl_xor(mx, off));
            mnew[r] = fmaxf(mrow[r], mx);
            resc[r] = exp2f(mrow[r] - mnew[r]);
            mrow[r] = mnew[r];
            psum[r] = 0.f;
        }
        ushort* pw = Ps[wave];
#pragma unroll
        for (int c = 0; c < 4; ++c)
#pragma unroll
            for (int r = 0; r < 4; ++r) {
                const float p = exp2f(sacc[c][r] - mnew[r]);
                psum[r] += p;
                pw[(4 * g + r) * 72 + c * 16 + lr] = f2bf(p);
            }
#pragma unroll
        for (int r = 0; r < 4; ++r) {
            float ps = psum[r];
#pragma unroll
            for (int off = 1; off < 16; off <<= 1) ps += __shfl_xor(ps, off);
            lrow[r] = lrow[r] * resc[r] + ps;
        }
#pragma unroll
        for (int c = 0; c < 4; ++c)
#pragma unroll
            for (int r = 0; r < 4; ++r) oacc[c][r] *= resc[r];

        // O += P V   (A-frag from per-wave P rows; B-frag from swizzled Vt rows)
#pragma unroll
        for (int s = 0; s < 2; ++s) {
            const bf16x8 pf = *(const bf16x8*)(pw + lr * 72 + s * 32 + g * 8);
#pragma unroll
            for (int c = 0; c < 4; ++c) {
                const int d = c * 16 + lr;
                const bf16x8 vf = *(const bf16x8*)(Vt + d * 64 + (((4 * s + g) ^ (d & 7)) << 3));
                oacc[c] = mfma16(pf, vf, oacc[c]);
            }
        }
    }

#pragma unroll
    for (int r = 0; r < 4; ++r) {
        const float inv = 1.0f / lrow[r];
        const size_t orow = (size_t)(b * 1024 + q0 + wave * 16 + 4 * g + r) * 1024 + h * 64;
#pragma unroll
        for (int c = 0; c < 4; ++c)
            o[orow + c * 16 + lr] = f2bf(oacc[c][r] * inv);
    }
}

// ---------------------------------------------------------------------------
extern "C" void kernel_launch(void* const* d_in, const int* in_sizes, int n_in,
                              void* d_out, int out_size, void* d_ws, size_t ws_size,
                              hipStream_t stream)
{
    const float* x      = (const float*)d_in[0];
    const float* qkv_w  = (const float*)d_in[1];
    const float* qkv_b  = (const float*)d_in[2];
    const float* out_w  = (const float*)d_in[3];
    const float* out_b  = (const float*)d_in[4];
    const float* ffn_w1 = (const float*)d_in[5];
    const float* ffn_b1 = (const float*)d_in[6];
    const float* ffn_w2 = (const float*)d_in[7];
    const float* ffn_b2 = (const float*)d_in[8];
    const float* ln1_g  = (const float*)d_in[9];
    const float* ln1_b  = (const float*)d_in[10];
    const float* ln2_g  = (const float*)d_in[11];
    const float* ln2_b  = (const float*)d_in[12];

    constexpr size_t MB = 1u << 20;
    char* ws = (char*)d_ws;
    ushort* wt_qkv = (ushort*)(ws + 0 * MB);     // [3072][1024] bf16  (6 MB)
    ushort* wt_out = (ushort*)(ws + 6 * MB);     // [1024][1024]       (2 MB)
    ushort* wt_f1  = (ushort*)(ws + 8 * MB);     // [4096][1024]       (8 MB)
    ushort* wt_f2  = (ushort*)(ws + 16 * MB);    // [1024][4096]       (8 MB)
    float*  x1     = (float*) (ws + 24 * MB);    // [8192][1024] f32   (32 MB)
    ushort* vtb    = (ushort*)(ws + 24 * MB);    // [128][64][1024]    (16 MB, aliases x1:
                                                 //  vtb dead before x1 written)
    ushort* hbuf   = (ushort*)(ws + 56 * MB);    // [8192][1024] bf16  (16 MB)
    ushort* qkvb   = (ushort*)(ws + 72 * MB);    // [8192][3072] bf16  (48 MB)
    ushort* obuf   = (ushort*)(ws + 120 * MB);   // [8192][1024] bf16  (16 MB)
    ushort* gbuf   = (ushort*)(ws + 72 * MB);    // [8192][4096] bf16  (64 MB, aliases qkvb+obuf)

    const dim3 tb(32, 8);
    transpose_w<<<dim3(3072 / 32, 1024 / 32), tb, 0, stream>>>(qkv_w,  wt_qkv, 1024, 3072);
    transpose_w<<<dim3(1024 / 32, 1024 / 32), tb, 0, stream>>>(out_w,  wt_out, 1024, 1024);
    transpose_w<<<dim3(4096 / 32, 1024 / 32), tb, 0, stream>>>(ffn_w1, wt_f1,  1024, 4096);
    transpose_w<<<dim3(1024 / 32, 4096 / 32), tb, 0, stream>>>(ffn_w2, wt_f2,  4096, 1024);

    ln_bf16<<<8192, 256, 0, stream>>>(x, ln1_g, ln1_b, hbuf);

    gemm_bt<0><<<dim3(3072 / 128, 8192 / 128), 256, 0, stream>>>(
        hbuf, wt_qkv, qkv_b, nullptr, qkvb, 8192, 3072, 1024);

    transpose_v<<<dim3(32, 2, 128), tb, 0, stream>>>(qkvb, vtb);

    attn_kernel<<<dim3(16, 128), 256, 0, stream>>>(qkvb, vtb, obuf);

    gemm_bt<1><<<dim3(1024 / 128, 8192 / 128), 256, 0, stream>>>(
        obuf, wt_out, out_b, x, x1, 8192, 1024, 1024);

    ln_bf16<<<8192, 256, 0, stream>>>(x1, ln2_g, ln2_b, hbuf);

    gemm_bt<2><<<dim3(4096 / 128, 8192 / 128), 256, 0, stream>>>(
        hbuf, wt_f1, ffn_b1, nullptr, gbuf, 8192, 4096, 1024);

    gemm_bt<1><<<dim3(1024 / 128, 8192 / 128), 256, 0, stream>>>(
        gbuf, wt_f2, ffn_b2, x1, (float*)d_out, 8192, 1024, 4096);
}

// Round 4
// 453.766 us; speedup vs baseline: 1.1614x; 1.0478x over previous
//
#include <hip/hip_runtime.h>
#include <hip/hip_bf16.h>

// ---------------------------------------------------------------------------
// Transformer block: LN1 -> QKV -> MHA(16 heads, Hd=64, N=1024) -> proj+res
//                    -> LN2 -> FFN(4096, exact gelu) + res
// B=8, N=1024, D=1024 -> 8192 tokens. All GEMMs in bf16 MFMA, f32 accum.
// ---------------------------------------------------------------------------

typedef float f32x4 __attribute__((ext_vector_type(4)));
typedef short bf16x8 __attribute__((ext_vector_type(8)));

#define DEV __device__ __forceinline__

DEV f32x4 mfma16(bf16x8 a, bf16x8 b, f32x4 c) {
    return __builtin_amdgcn_mfma_f32_16x16x32_bf16(a, b, c, 0, 0, 0);
}

DEV ushort f2bf(float f) {  // round-to-nearest-even f32 -> bf16
    union { float f; unsigned u; } v; v.f = f;
    unsigned r = v.u + 0x7FFFu + ((v.u >> 16) & 1u);
    return (ushort)(r >> 16);
}

DEV void gload_lds16(const void* g, void* l) {
    __builtin_amdgcn_global_load_lds(
        (const __attribute__((address_space(1))) void*)g,
        (__attribute__((address_space(3))) void*)l, 16, 0, 0);
}

// ---------------------------------------------------------------------------
// Weight transpose + cast: src [K][N] f32 -> dst [N][K] bf16
// ---------------------------------------------------------------------------
__global__ __launch_bounds__(256) void transpose_w(
    const float* __restrict__ src, ushort* __restrict__ dst, int K, int N)
{
    __shared__ float tile[32][33];
    const int n0 = blockIdx.x * 32, k0 = blockIdx.y * 32;
    const int tx = threadIdx.x, ty = threadIdx.y;
#pragma unroll
    for (int i = 0; i < 32; i += 8)
        tile[ty + i][tx] = src[(size_t)(k0 + ty + i) * N + n0 + tx];
    __syncthreads();
#pragma unroll
    for (int i = 0; i < 32; i += 8)
        dst[(size_t)(n0 + ty + i) * K + k0 + tx] = f2bf(tile[tx][ty + i]);
}

// ---------------------------------------------------------------------------
// V transpose: qkvb [b*1024+n][3072] (v at col 2048+h*64+d) -> vt[b][h][d][n]
// ---------------------------------------------------------------------------
__global__ __launch_bounds__(256) void transpose_v(
    const ushort* __restrict__ qkvb, ushort* __restrict__ vt)
{
    __shared__ ushort tile[32][33];
    const int b = blockIdx.z >> 4, h = blockIdx.z & 15;
    const int n0 = blockIdx.x * 32, d0 = blockIdx.y * 32;
    const int tx = threadIdx.x, ty = threadIdx.y;
#pragma unroll
    for (int i = 0; i < 32; i += 8)
        tile[ty + i][tx] =
            qkvb[(size_t)(b * 1024 + n0 + ty + i) * 3072 + 2048 + h * 64 + d0 + tx];
    __syncthreads();
#pragma unroll
    for (int i = 0; i < 32; i += 8)
        vt[((size_t)(b * 16 + h) * 64 + d0 + ty + i) * 1024 + n0 + tx] = tile[tx][ty + i];
}

// ---------------------------------------------------------------------------
// LayerNorm (D=1024): one block per row, f32 in -> bf16 out
// ---------------------------------------------------------------------------
__global__ __launch_bounds__(256) void ln_bf16(
    const float* __restrict__ x, const float* __restrict__ gw,
    const float* __restrict__ bw, ushort* __restrict__ out)
{
    const int row = blockIdx.x;
    const int t = threadIdx.x;
    const float4 v = ((const float4*)(x + (size_t)row * 1024))[t];
    float s  = v.x + v.y + v.z + v.w;
    float s2 = v.x * v.x + v.y * v.y + v.z * v.z + v.w * v.w;
#pragma unroll
    for (int off = 32; off; off >>= 1) {
        s  += __shfl_xor(s, off);
        s2 += __shfl_xor(s2, off);
    }
    __shared__ float red[16];
    const int wave = t >> 6, lane = t & 63;
    if (lane == 0) { red[wave] = s; red[8 + wave] = s2; }
    __syncthreads();
    s  = red[0] + red[1] + red[2] + red[3];
    s2 = red[8] + red[9] + red[10] + red[11];
    const float mean = s * (1.0f / 1024.0f);
    const float var  = s2 * (1.0f / 1024.0f) - mean * mean;
    const float rstd = rsqrtf(var + 1e-5f);
    const float4 gv = ((const float4*)gw)[t];
    const float4 bv = ((const float4*)bw)[t];
    ushort4 o;
    o.x = f2bf((v.x - mean) * rstd * gv.x + bv.x);
    o.y = f2bf((v.y - mean) * rstd * gv.y + bv.y);
    o.z = f2bf((v.z - mean) * rstd * gv.z + bv.z);
    o.w = f2bf((v.w - mean) * rstd * gv.w + bv.w);
    ((ushort4*)out)[(size_t)row * 256 + t] = o;
}

// ---------------------------------------------------------------------------
// GEMM: C[M,N] = A[M,K](bf16) @ BT[N,K]^T(bf16) + bias.
// 128x128 tile, BK=32, 4 waves (2x2), 4x4 16x16x32 MFMA frags per wave.
// 2-phase double-buffered pipeline (T3-minimum): issue next tile's
// global_load_lds before computing current tile; one vmcnt(0)+barrier
// (= __syncthreads) per K-step hides HBM/L2 latency under ds_read+MFMA.
// XCD-aware block swizzle (nwg % 8 == 0 for all our grids).
// EPI: 0 = bf16 out (bias), 1 = f32 out (bias + residual), 2 = bf16 gelu(bias)
// ---------------------------------------------------------------------------
template <int EPI>
__global__ __launch_bounds__(256) void gemm_bt(
    const ushort* __restrict__ A, const ushort* __restrict__ BT,
    const float* __restrict__ bias, const float* __restrict__ res,
    void* __restrict__ out, int M, int N, int K)
{
    __shared__ __align__(16) ushort As[2][128 * 32];
    __shared__ __align__(16) ushort Bs[2][128 * 32];

    const int tid = threadIdx.x;
    const int wave = tid >> 6, lane = tid & 63;
    const int g = lane >> 4, lr = lane & 15;
    const int wr = wave >> 1, wc = wave & 1;

    // XCD swizzle: dispatch d lands on XCD d%8; give each XCD a contiguous chunk
    const int gx = gridDim.x;
    const int nwg = gx * gridDim.y;
    int id = blockIdx.y * gx + blockIdx.x;
    id = (id & 7) * (nwg >> 3) + (id >> 3);
    const int m0 = (id / gx) * 128, n0 = (id % gx) * 128;

    f32x4 acc[4][4] = {};

    // staging: wave covers 2x16 rows of A and B; lane -> row l>>2, k (l&3)*8
    // (LDS dest = wave-uniform base + lane*16B, matching this linear order)
    const int srow = lane >> 2, skk = (lane & 3) * 8;
    const ushort* ag0 = A  + (size_t)(m0 + wave * 16       + srow) * K + skk;
    const ushort* ag1 = A  + (size_t)(m0 + (wave + 4) * 16 + srow) * K + skk;
    const ushort* bg0 = BT + (size_t)(n0 + wave * 16       + srow) * K + skk;
    const ushort* bg1 = BT + (size_t)(n0 + (wave + 4) * 16 + srow) * K + skk;

    const int nt = K >> 5;

    // prologue: stage tile 0 into buf 0
    {
        gload_lds16(ag0, As[0] + wave * 512);
        gload_lds16(ag1, As[0] + (wave + 4) * 512);
        gload_lds16(bg0, Bs[0] + wave * 512);
        gload_lds16(bg1, Bs[0] + (wave + 4) * 512);
    }
    __syncthreads();   // vmcnt(0) drain + barrier

    int cur = 0;
    for (int t = 0; t < nt; ++t) {
        // issue next tile's loads into the other buffer (async, in flight
        // across the compute below; drained by the end-of-iter barrier)
        if (t + 1 < nt) {
            const int kt = (t + 1) << 5;
            const int nx = cur ^ 1;
            gload_lds16(ag0 + kt, As[nx] + wave * 512);
            gload_lds16(ag1 + kt, As[nx] + (wave + 4) * 512);
            gload_lds16(bg0 + kt, Bs[nx] + wave * 512);
            gload_lds16(bg1 + kt, Bs[nx] + (wave + 4) * 512);
        }
        const ushort* as = As[cur];
        const ushort* bs = Bs[cur];
        bf16x8 af[4], bfv[4];
#pragma unroll
        for (int m = 0; m < 4; ++m)
            af[m] = *(const bf16x8*)(as + (wr * 64 + m * 16 + lr) * 32 + g * 8);
#pragma unroll
        for (int n = 0; n < 4; ++n)
            bfv[n] = *(const bf16x8*)(bs + (wc * 64 + n * 16 + lr) * 32 + g * 8);
#pragma unroll
        for (int m = 0; m < 4; ++m)
#pragma unroll
            for (int n = 0; n < 4; ++n)
                acc[m][n] = mfma16(af[m], bfv[n], acc[m][n]);
        __syncthreads();   // drains prefetch vmcnt(0) + barrier
        cur ^= 1;
    }

    // epilogue: C/D layout col = lr, row = 4*g + r
#pragma unroll
    for (int n = 0; n < 4; ++n) {
        const int col = n0 + wc * 64 + n * 16 + lr;
        const float bv = bias[col];
#pragma unroll
        for (int m = 0; m < 4; ++m) {
            const int row0 = m0 + wr * 64 + m * 16 + 4 * g;
#pragma unroll
            for (int r = 0; r < 4; ++r) {
                float v = acc[m][n][r] + bv;
                const size_t idx = (size_t)(row0 + r) * N + col;
                if constexpr (EPI == 1) {
                    ((float*)out)[idx] = v + res[idx];
                } else if constexpr (EPI == 2) {
                    v = 0.5f * v * (1.0f + erff(v * 0.70710678118654752f));
                    ((ushort*)out)[idx] = f2bf(v);
                } else {
                    ((ushort*)out)[idx] = f2bf(v);
                }
            }
        }
    }
}

// ---------------------------------------------------------------------------
// Flash attention: 2048 blocks (16 qtiles x 128 b*h), block 256 (4 waves).
// Q tile 64 rows (16/wave, in regs), K/V tiles 64 keys.
// K from qkv rows; V from pre-transposed vt[b][h][d][n]. Each thread stages
// TWO rows (sr and sr+32) per tile with vectorized bf16x8 swizzled writes.
// XCD swizzle groups all 16 q-tiles of one (b,h) onto one XCD for K/V L2 reuse.
// ---------------------------------------------------------------------------
__global__ __launch_bounds__(256) void attn_kernel(
    const ushort* __restrict__ qkv, const ushort* __restrict__ vtb,
    ushort* __restrict__ o)
{
    __shared__ __align__(16) ushort Ks[64 * 64];
    __shared__ __align__(16) ushort Vt[64 * 64];
    __shared__ __align__(16) ushort Ps[4][16 * 72];

    const int tid = threadIdx.x;
    const int wave = tid >> 6, lane = tid & 63;
    const int g = lane >> 4, lr = lane & 15;

    // XCD-aware remap (nwg=2048): logical id: qt fast, bh slow
    const int hwid = blockIdx.y * 16 + blockIdx.x;
    const int logical = (hwid & 7) * 256 + (hwid >> 3);
    const int qt = logical & 15, bh = logical >> 4;
    const int b = bh >> 4, h = bh & 15;
    const int q0 = qt * 64;

    const size_t base  = (size_t)b * 1024 * 3072;
    const size_t vbase = (size_t)bh * 64 * 1024;

    // Q fragments (A-operand), hoisted: row = lr of this wave's 16-row stripe
    const ushort* qp = qkv + base + (size_t)(q0 + wave * 16 + lr) * 3072 + h * 64;
    const bf16x8 qf0 = *(const bf16x8*)(qp + g * 8);
    const bf16x8 qf1 = *(const bf16x8*)(qp + 32 + g * 8);

    // staging: thread covers rows sr and sr+32 (0..63), 16B col-block sc (0..7)
    // (sr+32)&7 == sr&7 so the swizzle key is identical for both rows.
    const int sr = tid >> 3, sc = tid & 7;
    const int swz = (sc ^ (sr & 7)) << 3;
    const ushort* kg0 = qkv + base + (size_t)sr * 3072 + 1024 + h * 64 + sc * 8;
    const ushort* kg1 = kg0 + (size_t)32 * 3072;
    const ushort* vg0 = vtb + vbase + (size_t)sr * 1024 + sc * 8;
    const ushort* vg1 = vg0 + (size_t)32 * 1024;
    ushort* ksw0 = Ks + sr * 64 + swz;
    ushort* ksw1 = Ks + (sr + 32) * 64 + swz;
    ushort* vsw0 = Vt + sr * 64 + swz;
    ushort* vsw1 = Vt + (sr + 32) * 64 + swz;

    float mrow[4], lrow[4];
    f32x4 oacc[4] = {};
#pragma unroll
    for (int r = 0; r < 4; ++r) { mrow[r] = -1e30f; lrow[r] = 0.f; }

    constexpr float SCL = 0.18033688011112042f;  // Hd^-0.5 * log2(e)

    for (int kt = 0; kt < 16; ++kt) {
        const int n0 = kt * 64;
        __syncthreads();   // previous iter's LDS reads complete
        *(bf16x8*)ksw0 = *(const bf16x8*)(kg0 + (size_t)n0 * 3072);
        *(bf16x8*)ksw1 = *(const bf16x8*)(kg1 + (size_t)n0 * 3072);
        *(bf16x8*)vsw0 = *(const bf16x8*)(vg0 + n0);
        *(bf16x8*)vsw1 = *(const bf16x8*)(vg1 + n0);
        __syncthreads();

        // S = Q K^T  (B-frag: col = key c*16+lr, k = d)
        f32x4 sacc[4];
#pragma unroll
        for (int c = 0; c < 4; ++c) {
            f32x4 a = {0.f, 0.f, 0.f, 0.f};
            const int row = c * 16 + lr;
            a = mfma16(qf0, *(const bf16x8*)(Ks + row * 64 + ((g       ^ (lr & 7)) << 3)), a);
            a = mfma16(qf1, *(const bf16x8*)(Ks + row * 64 + (((4 + g) ^ (lr & 7)) << 3)), a);
            sacc[c] = a;
        }
#pragma unroll
        for (int c = 0; c < 4; ++c) sacc[c] *= SCL;  // log2-domain scores

        // online softmax (base 2): lane holds rows 4g+r, cols c*16+lr
        float mnew[4], resc[4], psum[4];
#pragma unroll
        for (int r = 0; r < 4; ++r) {
            float mx = fmaxf(fmaxf(sacc[0][r], sacc[1][r]),
                             fmaxf(sacc[2][r], sacc[3][r]));
#pragma unroll
            for (int off = 1; off < 16; off <<= 1) mx = fmaxf(mx, __shfl_xor(mx, off));
            mnew[r] = fmaxf(mrow[r], mx);
            resc[r] = exp2f(mrow[r] - mnew[r]);
            mrow[r] = mnew[r];
            psum[r] = 0.f;
        }
        ushort* pw = Ps[wave];
#pragma unroll
        for (int c = 0; c < 4; ++c)
#pragma unroll
            for (int r = 0; r < 4; ++r) {
                const float p = exp2f(sacc[c][r] - mnew[r]);
                psum[r] += p;
                pw[(4 * g + r) * 72 + c * 16 + lr] = f2bf(p);
            }
#pragma unroll
        for (int r = 0; r < 4; ++r) {
            float ps = psum[r];
#pragma unroll
            for (int off = 1; off < 16; off <<= 1) ps += __shfl_xor(ps, off);
            lrow[r] = lrow[r] * resc[r] + ps;
        }
#pragma unroll
        for (int c = 0; c < 4; ++c)
#pragma unroll
            for (int r = 0; r < 4; ++r) oacc[c][r] *= resc[r];

        // O += P V   (A-frag from per-wave P rows; B-frag from swizzled Vt rows)
#pragma unroll
        for (int s = 0; s < 2; ++s) {
            const bf16x8 pf = *(const bf16x8*)(pw + lr * 72 + s * 32 + g * 8);
#pragma unroll
            for (int c = 0; c < 4; ++c) {
                const int d = c * 16 + lr;
                const bf16x8 vf = *(const bf16x8*)(Vt + d * 64 + (((4 * s + g) ^ (d & 7)) << 3));
                oacc[c] = mfma16(pf, vf, oacc[c]);
            }
        }
    }

#pragma unroll
    for (int r = 0; r < 4; ++r) {
        const float inv = 1.0f / lrow[r];
        const size_t orow = (size_t)(b * 1024 + q0 + wave * 16 + 4 * g + r) * 1024 + h * 64;
#pragma unroll
        for (int c = 0; c < 4; ++c)
            o[orow + c * 16 + lr] = f2bf(oacc[c][r] * inv);
    }
}

// ---------------------------------------------------------------------------
extern "C" void kernel_launch(void* const* d_in, const int* in_sizes, int n_in,
                              void* d_out, int out_size, void* d_ws, size_t ws_size,
                              hipStream_t stream)
{
    const float* x      = (const float*)d_in[0];
    const float* qkv_w  = (const float*)d_in[1];
    const float* qkv_b  = (const float*)d_in[2];
    const float* out_w  = (const float*)d_in[3];
    const float* out_b  = (const float*)d_in[4];
    const float* ffn_w1 = (const float*)d_in[5];
    const float* ffn_b1 = (const float*)d_in[6];
    const float* ffn_w2 = (const float*)d_in[7];
    const float* ffn_b2 = (const float*)d_in[8];
    const float* ln1_g  = (const float*)d_in[9];
    const float* ln1_b  = (const float*)d_in[10];
    const float* ln2_g  = (const float*)d_in[11];
    const float* ln2_b  = (const float*)d_in[12];

    constexpr size_t MB = 1u << 20;
    char* ws = (char*)d_ws;
    ushort* wt_qkv = (ushort*)(ws + 0 * MB);     // [3072][1024] bf16  (6 MB)
    ushort* wt_out = (ushort*)(ws + 6 * MB);     // [1024][1024]       (2 MB)
    ushort* wt_f1  = (ushort*)(ws + 8 * MB);     // [4096][1024]       (8 MB)
    ushort* wt_f2  = (ushort*)(ws + 16 * MB);    // [1024][4096]       (8 MB)
    float*  x1     = (float*) (ws + 24 * MB);    // [8192][1024] f32   (32 MB)
    ushort* vtb    = (ushort*)(ws + 24 * MB);    // [128][64][1024]    (16 MB, aliases x1:
                                                 //  vtb dead before x1 written)
    ushort* hbuf   = (ushort*)(ws + 56 * MB);    // [8192][1024] bf16  (16 MB)
    ushort* qkvb   = (ushort*)(ws + 72 * MB);    // [8192][3072] bf16  (48 MB)
    ushort* obuf   = (ushort*)(ws + 120 * MB);   // [8192][1024] bf16  (16 MB)
    ushort* gbuf   = (ushort*)(ws + 72 * MB);    // [8192][4096] bf16  (64 MB, aliases qkvb+obuf)

    const dim3 tb(32, 8);
    transpose_w<<<dim3(3072 / 32, 1024 / 32), tb, 0, stream>>>(qkv_w,  wt_qkv, 1024, 3072);
    transpose_w<<<dim3(1024 / 32, 1024 / 32), tb, 0, stream>>>(out_w,  wt_out, 1024, 1024);
    transpose_w<<<dim3(4096 / 32, 1024 / 32), tb, 0, stream>>>(ffn_w1, wt_f1,  1024, 4096);
    transpose_w<<<dim3(1024 / 32, 4096 / 32), tb, 0, stream>>>(ffn_w2, wt_f2,  4096, 1024);

    ln_bf16<<<8192, 256, 0, stream>>>(x, ln1_g, ln1_b, hbuf);

    gemm_bt<0><<<dim3(3072 / 128, 8192 / 128), 256, 0, stream>>>(
        hbuf, wt_qkv, qkv_b, nullptr, qkvb, 8192, 3072, 1024);

    transpose_v<<<dim3(32, 2, 128), tb, 0, stream>>>(qkvb, vtb);

    attn_kernel<<<dim3(16, 128), 256, 0, stream>>>(qkvb, vtb, obuf);

    gemm_bt<1><<<dim3(1024 / 128, 8192 / 128), 256, 0, stream>>>(
        obuf, wt_out, out_b, x, x1, 8192, 1024, 1024);

    ln_bf16<<<8192, 256, 0, stream>>>(x1, ln2_g, ln2_b, hbuf);

    gemm_bt<2><<<dim3(4096 / 128, 8192 / 128), 256, 0, stream>>>(
        hbuf, wt_f1, ffn_b1, nullptr, gbuf, 8192, 4096, 1024);

    gemm_bt<1><<<dim3(1024 / 128, 8192 / 128), 256, 0, stream>>>(
        gbuf, wt_f2, ffn_b2, x1, (float*)d_out, 8192, 1024, 4096);
}

// Round 5
// 417.602 us; speedup vs baseline: 1.2620x; 1.0866x over previous
//
#include <hip/hip_runtime.h>
#include <hip/hip_bf16.h>

// ---------------------------------------------------------------------------
// Transformer block: LN1 -> QKV -> MHA(16 heads, Hd=64, N=1024) -> proj+res
//                    -> LN2 -> FFN(4096, exact gelu) + res
// B=8, N=1024, D=1024 -> 8192 tokens. All GEMMs in bf16 MFMA, f32 accum.
// ---------------------------------------------------------------------------

typedef float f32x4 __attribute__((ext_vector_type(4)));
typedef float f32x16 __attribute__((ext_vector_type(16)));
typedef short bf16x8 __attribute__((ext_vector_type(8)));

#define DEV __device__ __forceinline__

DEV f32x4 mfma16(bf16x8 a, bf16x8 b, f32x4 c) {
    return __builtin_amdgcn_mfma_f32_16x16x32_bf16(a, b, c, 0, 0, 0);
}

DEV f32x16 mfma32(bf16x8 a, bf16x8 b, f32x16 c) {
    return __builtin_amdgcn_mfma_f32_32x32x16_bf16(a, b, c, 0, 0, 0);
}

DEV ushort f2bf(float f) {  // round-to-nearest-even f32 -> bf16
    union { float f; unsigned u; } v; v.f = f;
    unsigned r = v.u + 0x7FFFu + ((v.u >> 16) & 1u);
    return (ushort)(r >> 16);
}

DEV unsigned cvtpk(float lo, float hi) {  // pack 2 f32 -> 2 bf16 in one u32
    unsigned r;
    asm("v_cvt_pk_bf16_f32 %0, %1, %2" : "=v"(r) : "v"(lo), "v"(hi));
    return r;
}

DEV void gload_lds16(const void* g, void* l) {
    __builtin_amdgcn_global_load_lds(
        (const __attribute__((address_space(1))) void*)g,
        (__attribute__((address_space(3))) void*)l, 16, 0, 0);
}

// ---------------------------------------------------------------------------
// Weight transpose + cast: src [K][N] f32 -> dst [N][K] bf16
// ---------------------------------------------------------------------------
__global__ __launch_bounds__(256) void transpose_w(
    const float* __restrict__ src, ushort* __restrict__ dst, int K, int N)
{
    __shared__ float tile[32][33];
    const int n0 = blockIdx.x * 32, k0 = blockIdx.y * 32;
    const int tx = threadIdx.x, ty = threadIdx.y;
#pragma unroll
    for (int i = 0; i < 32; i += 8)
        tile[ty + i][tx] = src[(size_t)(k0 + ty + i) * N + n0 + tx];
    __syncthreads();
#pragma unroll
    for (int i = 0; i < 32; i += 8)
        dst[(size_t)(n0 + ty + i) * K + k0 + tx] = f2bf(tile[tx][ty + i]);
}

// ---------------------------------------------------------------------------
// V transpose: qkvb [b*1024+n][3072] (v at col 2048+h*64+d) -> vt[b][h][d][n]
// ---------------------------------------------------------------------------
__global__ __launch_bounds__(256) void transpose_v(
    const ushort* __restrict__ qkvb, ushort* __restrict__ vt)
{
    __shared__ ushort tile[32][33];
    const int b = blockIdx.z >> 4, h = blockIdx.z & 15;
    const int n0 = blockIdx.x * 32, d0 = blockIdx.y * 32;
    const int tx = threadIdx.x, ty = threadIdx.y;
#pragma unroll
    for (int i = 0; i < 32; i += 8)
        tile[ty + i][tx] =
            qkvb[(size_t)(b * 1024 + n0 + ty + i) * 3072 + 2048 + h * 64 + d0 + tx];
    __syncthreads();
#pragma unroll
    for (int i = 0; i < 32; i += 8)
        vt[((size_t)(b * 16 + h) * 64 + d0 + ty + i) * 1024 + n0 + tx] = tile[tx][ty + i];
}

// ---------------------------------------------------------------------------
// LayerNorm (D=1024): one block per row, f32 in -> bf16 out
// ---------------------------------------------------------------------------
__global__ __launch_bounds__(256) void ln_bf16(
    const float* __restrict__ x, const float* __restrict__ gw,
    const float* __restrict__ bw, ushort* __restrict__ out)
{
    const int row = blockIdx.x;
    const int t = threadIdx.x;
    const float4 v = ((const float4*)(x + (size_t)row * 1024))[t];
    float s  = v.x + v.y + v.z + v.w;
    float s2 = v.x * v.x + v.y * v.y + v.z * v.z + v.w * v.w;
#pragma unroll
    for (int off = 32; off; off >>= 1) {
        s  += __shfl_xor(s, off);
        s2 += __shfl_xor(s2, off);
    }
    __shared__ float red[16];
    const int wave = t >> 6, lane = t & 63;
    if (lane == 0) { red[wave] = s; red[8 + wave] = s2; }
    __syncthreads();
    s  = red[0] + red[1] + red[2] + red[3];
    s2 = red[8] + red[9] + red[10] + red[11];
    const float mean = s * (1.0f / 1024.0f);
    const float var  = s2 * (1.0f / 1024.0f) - mean * mean;
    const float rstd = rsqrtf(var + 1e-5f);
    const float4 gv = ((const float4*)gw)[t];
    const float4 bv = ((const float4*)bw)[t];
    ushort4 o;
    o.x = f2bf((v.x - mean) * rstd * gv.x + bv.x);
    o.y = f2bf((v.y - mean) * rstd * gv.y + bv.y);
    o.z = f2bf((v.z - mean) * rstd * gv.z + bv.z);
    o.w = f2bf((v.w - mean) * rstd * gv.w + bv.w);
    ((ushort4*)out)[(size_t)row * 256 + t] = o;
}

// ---------------------------------------------------------------------------
// GEMM: C[M,N] = A[M,K](bf16) @ BT[N,K]^T(bf16) + bias.
// 128x128 tile, BK=32, 4 waves (2x2), 2-phase double-buffered pipeline.
// XCD-aware block swizzle (nwg % 8 == 0 for all our grids).
// EPI: 0 = bf16 out (bias), 1 = f32 out (bias + residual), 2 = bf16 gelu(bias)
// ---------------------------------------------------------------------------
template <int EPI>
__global__ __launch_bounds__(256) void gemm_bt(
    const ushort* __restrict__ A, const ushort* __restrict__ BT,
    const float* __restrict__ bias, const float* __restrict__ res,
    void* __restrict__ out, int M, int N, int K)
{
    __shared__ __align__(16) ushort As[2][128 * 32];
    __shared__ __align__(16) ushort Bs[2][128 * 32];

    const int tid = threadIdx.x;
    const int wave = tid >> 6, lane = tid & 63;
    const int g = lane >> 4, lr = lane & 15;
    const int wr = wave >> 1, wc = wave & 1;

    // XCD swizzle: dispatch d lands on XCD d%8; give each XCD a contiguous chunk
    const int gx = gridDim.x;
    const int nwg = gx * gridDim.y;
    int id = blockIdx.y * gx + blockIdx.x;
    id = (id & 7) * (nwg >> 3) + (id >> 3);
    const int m0 = (id / gx) * 128, n0 = (id % gx) * 128;

    f32x4 acc[4][4] = {};

    // staging: wave covers 2x16 rows of A and B; lane -> row l>>2, k (l&3)*8
    const int srow = lane >> 2, skk = (lane & 3) * 8;
    const ushort* ag0 = A  + (size_t)(m0 + wave * 16       + srow) * K + skk;
    const ushort* ag1 = A  + (size_t)(m0 + (wave + 4) * 16 + srow) * K + skk;
    const ushort* bg0 = BT + (size_t)(n0 + wave * 16       + srow) * K + skk;
    const ushort* bg1 = BT + (size_t)(n0 + (wave + 4) * 16 + srow) * K + skk;

    const int nt = K >> 5;

    // prologue: stage tile 0 into buf 0
    {
        gload_lds16(ag0, As[0] + wave * 512);
        gload_lds16(ag1, As[0] + (wave + 4) * 512);
        gload_lds16(bg0, Bs[0] + wave * 512);
        gload_lds16(bg1, Bs[0] + (wave + 4) * 512);
    }
    __syncthreads();   // vmcnt(0) drain + barrier

    int cur = 0;
    for (int t = 0; t < nt; ++t) {
        if (t + 1 < nt) {
            const int kt = (t + 1) << 5;
            const int nx = cur ^ 1;
            gload_lds16(ag0 + kt, As[nx] + wave * 512);
            gload_lds16(ag1 + kt, As[nx] + (wave + 4) * 512);
            gload_lds16(bg0 + kt, Bs[nx] + wave * 512);
            gload_lds16(bg1 + kt, Bs[nx] + (wave + 4) * 512);
        }
        const ushort* as = As[cur];
        const ushort* bs = Bs[cur];
        bf16x8 af[4], bfv[4];
#pragma unroll
        for (int m = 0; m < 4; ++m)
            af[m] = *(const bf16x8*)(as + (wr * 64 + m * 16 + lr) * 32 + g * 8);
#pragma unroll
        for (int n = 0; n < 4; ++n)
            bfv[n] = *(const bf16x8*)(bs + (wc * 64 + n * 16 + lr) * 32 + g * 8);
#pragma unroll
        for (int m = 0; m < 4; ++m)
#pragma unroll
            for (int n = 0; n < 4; ++n)
                acc[m][n] = mfma16(af[m], bfv[n], acc[m][n]);
        __syncthreads();   // drains prefetch vmcnt(0) + barrier
        cur ^= 1;
    }

    // epilogue: C/D layout col = lr, row = 4*g + r
#pragma unroll
    for (int n = 0; n < 4; ++n) {
        const int col = n0 + wc * 64 + n * 16 + lr;
        const float bv = bias[col];
#pragma unroll
        for (int m = 0; m < 4; ++m) {
            const int row0 = m0 + wr * 64 + m * 16 + 4 * g;
#pragma unroll
            for (int r = 0; r < 4; ++r) {
                float v = acc[m][n][r] + bv;
                const size_t idx = (size_t)(row0 + r) * N + col;
                if constexpr (EPI == 1) {
                    ((float*)out)[idx] = v + res[idx];
                } else if constexpr (EPI == 2) {
                    v = 0.5f * v * (1.0f + erff(v * 0.70710678118654752f));
                    ((ushort*)out)[idx] = f2bf(v);
                } else {
                    ((ushort*)out)[idx] = f2bf(v);
                }
            }
        }
    }
}

// ---------------------------------------------------------------------------
// Flash attention, swapped-operand 32x32 structure (m214-style):
// grid 1024 blocks (8 qtiles x 128 b*h), 4 waves x 32 q-rows = 128 q/block.
// S^T = mfma32(K, Q): lane holds P[key pattern][q = lane&31] -> softmax fully
// in-register (fmax chain + one shfl_xor(32)); P -> bf16 via v_cvt_pk feeds
// PV's B-operand DIRECTLY (C/D key layout == B-frag k layout). PV swapped:
// O^T = mfma32(V^T, P) so rescale factor is lane-local.
// K/V tiles (64 keys) staged in LDS with XOR swizzle as before.
// ---------------------------------------------------------------------------
__global__ __launch_bounds__(256) void attn_kernel(
    const ushort* __restrict__ qkv, const ushort* __restrict__ vtb,
    ushort* __restrict__ o)
{
    __shared__ __align__(16) ushort Ks[64 * 64];
    __shared__ __align__(16) ushort Vt[64 * 64];

    const int tid = threadIdx.x;
    const int wave = tid >> 6, lane = tid & 63;
    const int lq = lane & 31;         // this lane's q within the wave's 32 rows
    const int hi = lane >> 5;         // lane half: key/d quad offset 4*hi
    const int l7 = lane & 7;

    // XCD-aware remap (nwg=1024): 8 qtiles of one (b,h) stay on one XCD
    const int hwid = blockIdx.x;
    const int logical = (hwid & 7) * 128 + (hwid >> 3);
    const int bh = logical >> 3, qt = logical & 7;
    const int b = bh >> 4, head = bh & 15;
    const int q0 = qt * 128 + wave * 32;

    const size_t base  = (size_t)b * 1024 * 3072;
    const size_t vbase = (size_t)bh * 64 * 1024;

    union BF8 { bf16x8 v; ushort u[8]; unsigned w[4]; };

    // Q as B-operand, hoisted: slot s covers d=16s..16s+15;
    // reg j = Q[d = (j&3)+8*(j>>2)+4*hi + 16s][q0+lq]
    BF8 qf[4];
    {
        const ushort* qrow = qkv + base + (size_t)(q0 + lq) * 3072 + head * 64;
#pragma unroll
        for (int s = 0; s < 4; ++s) {
            *(ushort4*)&qf[s].u[0] = *(const ushort4*)(qrow + 16 * s + 4 * hi);
            *(ushort4*)&qf[s].u[4] = *(const ushort4*)(qrow + 16 * s + 8 + 4 * hi);
        }
    }

    // staging: thread covers rows sr and sr+32, 16B col-block sc (0..7)
    const int sr = tid >> 3, sc = tid & 7;
    const int swz = (sc ^ (sr & 7)) << 3;
    const ushort* kg0 = qkv + base + (size_t)sr * 3072 + 1024 + head * 64 + sc * 8;
    const ushort* kg1 = kg0 + (size_t)32 * 3072;
    const ushort* vg0 = vtb + vbase + (size_t)sr * 1024 + sc * 8;
    const ushort* vg1 = vg0 + (size_t)32 * 1024;
    ushort* ksw0 = Ks + sr * 64 + swz;
    ushort* ksw1 = Ks + (sr + 32) * 64 + swz;
    ushort* vsw0 = Vt + sr * 64 + swz;
    ushort* vsw1 = Vt + (sr + 32) * 64 + swz;

    float m_st = -1e30f, l_st = 0.f;
    f32x16 oacc[2] = {};   // O^T: lane holds O[d=(r&3)+8*(r>>2)+4hi+32nb][q0+lq]

    constexpr float SCL = 0.18033688011112042f;  // Hd^-0.5 * log2(e)

    for (int kt = 0; kt < 16; ++kt) {
        const int n0 = kt * 64;
        __syncthreads();   // previous iter's LDS reads complete
        *(bf16x8*)ksw0 = *(const bf16x8*)(kg0 + (size_t)n0 * 3072);
        *(bf16x8*)ksw1 = *(const bf16x8*)(kg1 + (size_t)n0 * 3072);
        *(bf16x8*)vsw0 = *(const bf16x8*)(vg0 + n0);
        *(bf16x8*)vsw1 = *(const bf16x8*)(vg1 + n0);
        __syncthreads();

        // S^T = K·Q: kb = 32-key block; lane holds S[key=(r&3)+8*(r>>2)+4hi+32kb][q0+lq]
        f32x16 sacc[2];
#pragma unroll
        for (int kb = 0; kb < 2; ++kb) {
            f32x16 a = {};
            const ushort* krow = Ks + (kb * 32 + lq) * 64;
#pragma unroll
            for (int s = 0; s < 4; ++s) {
                BF8 kf;
                *(ushort4*)&kf.u[0] = *(const ushort4*)(krow + (((2 * s)     ^ l7) << 3) + 4 * hi);
                *(ushort4*)&kf.u[4] = *(const ushort4*)(krow + (((2 * s + 1) ^ l7) << 3) + 4 * hi);
                a = mfma32(kf.v, qf[s].v, a);
            }
            sacc[kb] = a;
        }

        // online softmax over 64 keys (lane + lane^32 hold the same q)
        float mloc = -1e30f;
#pragma unroll
        for (int kb = 0; kb < 2; ++kb)
#pragma unroll
            for (int r = 0; r < 16; ++r)
                mloc = fmaxf(mloc, sacc[kb][r]);
        mloc = fmaxf(mloc, __shfl_xor(mloc, 32));
        const float mnew = fmaxf(m_st, mloc * SCL);
        const float resc = exp2f(m_st - mnew);
        m_st = mnew;

        float psum = 0.f;
#pragma unroll
        for (int kb = 0; kb < 2; ++kb)
#pragma unroll
            for (int r = 0; r < 16; ++r) {
                const float pe = exp2f(fmaf(sacc[kb][r], SCL, -mnew));
                sacc[kb][r] = pe;   // in-place: sacc becomes P
                psum += pe;
            }
        psum += __shfl_xor(psum, 32);
        l_st = l_st * resc + psum;
#pragma unroll
        for (int nb = 0; nb < 2; ++nb)
#pragma unroll
            for (int r = 0; r < 16; ++r)
                oacc[nb][r] *= resc;

        // PV: O^T[d][q] += V^T[d][key] · P[key][q]; P regs feed B directly
#pragma unroll
        for (int kb = 0; kb < 2; ++kb) {
            BF8 pf[2];
#pragma unroll
            for (int t = 0; t < 2; ++t)
#pragma unroll
                for (int w = 0; w < 4; ++w)
                    pf[t].w[w] = cvtpk(sacc[kb][8 * t + 2 * w], sacc[kb][8 * t + 2 * w + 1]);
#pragma unroll
            for (int nb = 0; nb < 2; ++nb) {
                const ushort* vrow = Vt + (nb * 32 + lq) * 64;
#pragma unroll
                for (int t = 0; t < 2; ++t) {
                    BF8 vf;
                    const int blk = 4 * kb + 2 * t;
                    *(ushort4*)&vf.u[0] = *(const ushort4*)(vrow + ((blk       ^ l7) << 3) + 4 * hi);
                    *(ushort4*)&vf.u[4] = *(const ushort4*)(vrow + (((blk + 1) ^ l7) << 3) + 4 * hi);
                    oacc[nb] = mfma32(vf.v, pf[t].v, oacc[nb]);
                }
            }
        }
    }

    // epilogue: lane writes its q-row; d quads are contiguous (4 bf16 = 8B)
    const float inv = 1.0f / l_st;
    ushort* orow = o + (size_t)(b * 1024 + q0 + lq) * 1024 + head * 64;
#pragma unroll
    for (int nb = 0; nb < 2; ++nb)
#pragma unroll
        for (int u = 0; u < 4; ++u) {
            uint2 wv;
            wv.x = cvtpk(oacc[nb][4 * u] * inv,     oacc[nb][4 * u + 1] * inv);
            wv.y = cvtpk(oacc[nb][4 * u + 2] * inv, oacc[nb][4 * u + 3] * inv);
            *(uint2*)(orow + nb * 32 + 8 * u + 4 * hi) = wv;
        }
}

// ---------------------------------------------------------------------------
extern "C" void kernel_launch(void* const* d_in, const int* in_sizes, int n_in,
                              void* d_out, int out_size, void* d_ws, size_t ws_size,
                              hipStream_t stream)
{
    const float* x      = (const float*)d_in[0];
    const float* qkv_w  = (const float*)d_in[1];
    const float* qkv_b  = (const float*)d_in[2];
    const float* out_w  = (const float*)d_in[3];
    const float* out_b  = (const float*)d_in[4];
    const float* ffn_w1 = (const float*)d_in[5];
    const float* ffn_b1 = (const float*)d_in[6];
    const float* ffn_w2 = (const float*)d_in[7];
    const float* ffn_b2 = (const float*)d_in[8];
    const float* ln1_g  = (const float*)d_in[9];
    const float* ln1_b  = (const float*)d_in[10];
    const float* ln2_g  = (const float*)d_in[11];
    const float* ln2_b  = (const float*)d_in[12];

    constexpr size_t MB = 1u << 20;
    char* ws = (char*)d_ws;
    ushort* wt_qkv = (ushort*)(ws + 0 * MB);     // [3072][1024] bf16  (6 MB)
    ushort* wt_out = (ushort*)(ws + 6 * MB);     // [1024][1024]       (2 MB)
    ushort* wt_f1  = (ushort*)(ws + 8 * MB);     // [4096][1024]       (8 MB)
    ushort* wt_f2  = (ushort*)(ws + 16 * MB);    // [1024][4096]       (8 MB)
    float*  x1     = (float*) (ws + 24 * MB);    // [8192][1024] f32   (32 MB)
    ushort* vtb    = (ushort*)(ws + 24 * MB);    // [128][64][1024]    (16 MB, aliases x1:
                                                 //  vtb dead before x1 written)
    ushort* hbuf   = (ushort*)(ws + 56 * MB);    // [8192][1024] bf16  (16 MB)
    ushort* qkvb   = (ushort*)(ws + 72 * MB);    // [8192][3072] bf16  (48 MB)
    ushort* obuf   = (ushort*)(ws + 120 * MB);   // [8192][1024] bf16  (16 MB)
    ushort* gbuf   = (ushort*)(ws + 72 * MB);    // [8192][4096] bf16  (64 MB, aliases qkvb+obuf)

    const dim3 tb(32, 8);
    transpose_w<<<dim3(3072 / 32, 1024 / 32), tb, 0, stream>>>(qkv_w,  wt_qkv, 1024, 3072);
    transpose_w<<<dim3(1024 / 32, 1024 / 32), tb, 0, stream>>>(out_w,  wt_out, 1024, 1024);
    transpose_w<<<dim3(4096 / 32, 1024 / 32), tb, 0, stream>>>(ffn_w1, wt_f1,  1024, 4096);
    transpose_w<<<dim3(1024 / 32, 4096 / 32), tb, 0, stream>>>(ffn_w2, wt_f2,  4096, 1024);

    ln_bf16<<<8192, 256, 0, stream>>>(x, ln1_g, ln1_b, hbuf);

    gemm_bt<0><<<dim3(3072 / 128, 8192 / 128), 256, 0, stream>>>(
        hbuf, wt_qkv, qkv_b, nullptr, qkvb, 8192, 3072, 1024);

    transpose_v<<<dim3(32, 2, 128), tb, 0, stream>>>(qkvb, vtb);

    attn_kernel<<<1024, 256, 0, stream>>>(qkvb, vtb, obuf);

    gemm_bt<1><<<dim3(1024 / 128, 8192 / 128), 256, 0, stream>>>(
        obuf, wt_out, out_b, x, x1, 8192, 1024, 1024);

    ln_bf16<<<8192, 256, 0, stream>>>(x1, ln2_g, ln2_b, hbuf);

    gemm_bt<2><<<dim3(4096 / 128, 8192 / 128), 256, 0, stream>>>(
        hbuf, wt_f1, ffn_b1, nullptr, gbuf, 8192, 4096, 1024);

    gemm_bt<1><<<dim3(1024 / 128, 8192 / 128), 256, 0, stream>>>(
        gbuf, wt_f2, ffn_b2, x1, (float*)d_out, 8192, 1024, 4096);
}

// Round 7
// 388.354 us; speedup vs baseline: 1.3570x; 1.0753x over previous
//
#include <hip/hip_runtime.h>
#include <hip/hip_bf16.h>

// ---------------------------------------------------------------------------
// Transformer block: LN1 -> QKV -> MHA(16 heads, Hd=64, N=1024) -> proj+res
//                    -> LN2 -> FFN(4096, exact gelu) + res
// B=8, N=1024, D=1024 -> 8192 tokens. All GEMMs in bf16 MFMA, f32 accum.
// GEMMs: 8-phase deep-pipelined 256-tile schedule (T2+T3+T4+T5).
// ---------------------------------------------------------------------------

typedef float f32x4 __attribute__((ext_vector_type(4)));
typedef float f32x16 __attribute__((ext_vector_type(16)));
typedef short bf16x8 __attribute__((ext_vector_type(8)));

#define DEV __device__ __forceinline__

DEV f32x4 mfma16(bf16x8 a, bf16x8 b, f32x4 c) {
    return __builtin_amdgcn_mfma_f32_16x16x32_bf16(a, b, c, 0, 0, 0);
}

DEV f32x16 mfma32(bf16x8 a, bf16x8 b, f32x16 c) {
    return __builtin_amdgcn_mfma_f32_32x32x16_bf16(a, b, c, 0, 0, 0);
}

DEV ushort f2bf(float f) {  // round-to-nearest-even f32 -> bf16
    union { float f; unsigned u; } v; v.f = f;
    unsigned r = v.u + 0x7FFFu + ((v.u >> 16) & 1u);
    return (ushort)(r >> 16);
}

DEV unsigned cvtpk(float lo, float hi) {  // pack 2 f32 -> 2 bf16 in one u32
    unsigned r;
    asm("v_cvt_pk_bf16_f32 %0, %1, %2" : "=v"(r) : "v"(lo), "v"(hi));
    return r;
}

DEV void gload_lds16(const void* g, void* l) {
    __builtin_amdgcn_global_load_lds(
        (const __attribute__((address_space(1))) void*)g,
        (__attribute__((address_space(3))) void*)l, 16, 0, 0);
}

template <int N> DEV void vmw() {
    if constexpr (N == 0)      asm volatile("s_waitcnt vmcnt(0)" ::: "memory");
    else if constexpr (N == 3) asm volatile("s_waitcnt vmcnt(3)" ::: "memory");
    else if constexpr (N == 4) asm volatile("s_waitcnt vmcnt(4)" ::: "memory");
    __builtin_amdgcn_sched_barrier(0);
}

#define SBAR() do { __builtin_amdgcn_sched_barrier(0); \
                    __builtin_amdgcn_s_barrier(); \
                    __builtin_amdgcn_sched_barrier(0); } while (0)
#define LGKM0() do { asm volatile("s_waitcnt lgkmcnt(0)" ::: "memory"); \
                     __builtin_amdgcn_sched_barrier(0); } while (0)

// ---------------------------------------------------------------------------
// Weight transpose + cast: src [K][N] f32 -> dst [N][K] bf16
// ---------------------------------------------------------------------------
__global__ __launch_bounds__(256) void transpose_w(
    const float* __restrict__ src, ushort* __restrict__ dst, int K, int N)
{
    __shared__ float tile[32][33];
    const int n0 = blockIdx.x * 32, k0 = blockIdx.y * 32;
    const int tx = threadIdx.x, ty = threadIdx.y;
#pragma unroll
    for (int i = 0; i < 32; i += 8)
        tile[ty + i][tx] = src[(size_t)(k0 + ty + i) * N + n0 + tx];
    __syncthreads();
#pragma unroll
    for (int i = 0; i < 32; i += 8)
        dst[(size_t)(n0 + ty + i) * K + k0 + tx] = f2bf(tile[tx][ty + i]);
}

// ---------------------------------------------------------------------------
// V transpose: qkvb [b*1024+n][3072] (v at col 2048+h*64+d) -> vt[b][h][d][n]
// ---------------------------------------------------------------------------
__global__ __launch_bounds__(256) void transpose_v(
    const ushort* __restrict__ qkvb, ushort* __restrict__ vt)
{
    __shared__ ushort tile[32][33];
    const int b = blockIdx.z >> 4, h = blockIdx.z & 15;
    const int n0 = blockIdx.x * 32, d0 = blockIdx.y * 32;
    const int tx = threadIdx.x, ty = threadIdx.y;
#pragma unroll
    for (int i = 0; i < 32; i += 8)
        tile[ty + i][tx] =
            qkvb[(size_t)(b * 1024 + n0 + ty + i) * 3072 + 2048 + h * 64 + d0 + tx];
    __syncthreads();
#pragma unroll
    for (int i = 0; i < 32; i += 8)
        vt[((size_t)(b * 16 + h) * 64 + d0 + ty + i) * 1024 + n0 + tx] = tile[tx][ty + i];
}

// ---------------------------------------------------------------------------
// LayerNorm (D=1024): one block per row, f32 in -> bf16 out
// ---------------------------------------------------------------------------
__global__ __launch_bounds__(256) void ln_bf16(
    const float* __restrict__ x, const float* __restrict__ gw,
    const float* __restrict__ bw, ushort* __restrict__ out)
{
    const int row = blockIdx.x;
    const int t = threadIdx.x;
    const float4 v = ((const float4*)(x + (size_t)row * 1024))[t];
    float s  = v.x + v.y + v.z + v.w;
    float s2 = v.x * v.x + v.y * v.y + v.z * v.z + v.w * v.w;
#pragma unroll
    for (int off = 32; off; off >>= 1) {
        s  += __shfl_xor(s, off);
        s2 += __shfl_xor(s2, off);
    }
    __shared__ float red[16];
    const int wave = t >> 6, lane = t & 63;
    if (lane == 0) { red[wave] = s; red[8 + wave] = s2; }
    __syncthreads();
    s  = red[0] + red[1] + red[2] + red[3];
    s2 = red[8] + red[9] + red[10] + red[11];
    const float mean = s * (1.0f / 1024.0f);
    const float var  = s2 * (1.0f / 1024.0f) - mean * mean;
    const float rstd = rsqrtf(var + 1e-5f);
    const float4 gv = ((const float4*)gw)[t];
    const float4 bv = ((const float4*)bw)[t];
    ushort4 o;
    o.x = f2bf((v.x - mean) * rstd * gv.x + bv.x);
    o.y = f2bf((v.y - mean) * rstd * gv.y + bv.y);
    o.z = f2bf((v.z - mean) * rstd * gv.z + bv.z);
    o.w = f2bf((v.w - mean) * rstd * gv.w + bv.w);
    ((ushort4*)out)[(size_t)row * 256 + t] = o;
}

// ---------------------------------------------------------------------------
// 8-phase GEMM: C[M,N] = A[M,K](bf16) @ BT[N,K]^T(bf16) + bias.
// BMxBN tile, BK=64, 8 waves (WM_ x WN_), 512 threads, double-buffered LDS.
// Per K-tile: 4 phases, each = one C-quadrant (mh,nh) x K=64 with cycle
// (0,0)(0,1)(1,1)(1,0); B-frags register-cached so each LDS half is read in
// exactly one phase. Stage slots: ph0->(k+1).B1, ph1->(k+1).A1,
// ph2->(k+2).A0, ph3->(k+2).B0. One counted vmcnt(LA+LB) per tile (at ph3,
// before end barrier) lands all halves of tile k+1 (FIFO vmcnt). LDS XOR
// swizzle blk^=row&7 via pre-swizzled global source + swizzled ds_read.
// EPI: 0 = bf16 out (bias), 1 = f32 out (bias + residual), 2 = bf16 gelu(bias)
// ---------------------------------------------------------------------------
template <int BM, int BN, int WM_, int WN_, int EPI>
__global__ __launch_bounds__(512, 2) void gemm8p(
    const ushort* __restrict__ A, const ushort* __restrict__ BT,
    const float* __restrict__ bias, const float* __restrict__ res,
    void* __restrict__ out, int M, int N, int K)
{
    constexpr int BK = 64;
    constexpr int MR = BM / WM_ / 16;      // A frag repeats per wave
    constexpr int NR = BN / WN_ / 16;      // B frag repeats per wave
    constexpr int MQ = MR / 2, NQ = NR / 2;
    constexpr int LA = (BM / 2) * BK * 2 / (512 * 16);  // loads per A half
    constexpr int LB = (BN / 2) * BK * 2 / (512 * 16);  // loads per B half
    constexpr int VMN = LA + LB;
    constexpr int ABYTES = BM * BK * 2;
    constexpr int BBYTES = BN * BK * 2;

    extern __shared__ __align__(16) char smem[];
    // NOTE: no pointer arrays here — clang can't static-init aggregates with
    // LDS addrspacecasts. Compute buffer bases at each use instead.
#define ASB(buf) (smem + (buf) * ABYTES)
#define BSB(buf) (smem + 2 * ABYTES + (buf) * BBYTES)

    const int tid = threadIdx.x;
    const int wave = tid >> 6, lane = tid & 63;
    const int g = lane >> 4, lr = lane & 15;
    const int wr = wave / WN_, wc = wave % WN_;
    const int akey = (lr & 7) << 4;

    // XCD swizzle (nwg % 8 == 0 for all grids here)
    const int gx = gridDim.x;
    const int nwg = gx * gridDim.y;
    int id = blockIdx.y * gx + blockIdx.x;
    id = (id & 7) * (nwg >> 3) + (id >> 3);
    const int m0 = (id / gx) * BM, n0 = (id % gx) * BN;

    // staging source (pre-swizzled): thread covers row trow (+64 per i),
    // 16B block tblk within the row; inverse-swizzle is the same XOR.
    const int trow = tid >> 3;
    const int tblk = (tid & 7) ^ (trow & 7);
    const ushort* pA = A  + (size_t)(m0 + trow) * K + tblk * 8;
    const ushort* pB = BT + (size_t)(n0 + trow) * K + tblk * 8;
    const int woff = wave * 1024;   // uniform LDS byte offset of this wave

#define STAGE_A(buf, mh, kt) do { \
    _Pragma("unroll") for (int i = 0; i < LA; ++i) \
        gload_lds16(pA + ((size_t)((mh) * (BM / 2) + i * 64)) * K + (kt) * 64, \
                    ASB(buf) + (mh) * (BM / 2) * 128 + i * 8192 + woff); \
} while (0)
#define STAGE_B(buf, nh, kt) do { \
    _Pragma("unroll") for (int i = 0; i < LB; ++i) \
        gload_lds16(pB + ((size_t)((nh) * (BN / 2) + i * 64)) * K + (kt) * 64, \
                    BSB(buf) + (nh) * (BN / 2) * 128 + i * 8192 + woff); \
} while (0)

    bf16x8 af[MQ][2], bf[NR][2];
    f32x4 acc[MR][NR] = {};

#define LOAD_A(buf, mh) do { \
    const char* hb_ = ASB(buf) + (mh) * (BM / 2) * 128 + (wr * (MQ * 16) + lr) * 128; \
    _Pragma("unroll") for (int mt = 0; mt < MQ; ++mt) \
    _Pragma("unroll") for (int kk = 0; kk < 2; ++kk) \
        af[mt][kk] = *(const bf16x8*)(hb_ + mt * 2048 + ((kk * 64 + g * 16) ^ akey)); \
} while (0)
#define LOAD_B(buf, nh) do { \
    const char* hb_ = BSB(buf) + (nh) * (BN / 2) * 128 + (wc * (NQ * 16) + lr) * 128; \
    _Pragma("unroll") for (int nt = 0; nt < NQ; ++nt) \
    _Pragma("unroll") for (int kk = 0; kk < 2; ++kk) \
        bf[(nh) * NQ + nt][kk] = *(const bf16x8*)(hb_ + nt * 2048 + ((kk * 64 + g * 16) ^ akey)); \
} while (0)
#define MFMA_Q(MH, NH) do { \
    __builtin_amdgcn_s_setprio(1); \
    _Pragma("unroll") for (int mt = 0; mt < MQ; ++mt) \
    _Pragma("unroll") for (int nt = 0; nt < NQ; ++nt) \
    _Pragma("unroll") for (int kk = 0; kk < 2; ++kk) \
        acc[(MH) * MQ + mt][(NH) * NQ + nt] = \
            mfma16(af[mt][kk], bf[(NH) * NQ + nt][kk], acc[(MH) * MQ + mt][(NH) * NQ + nt]); \
    __builtin_amdgcn_s_setprio(0); \
} while (0)

    const int NT = K >> 6;

    // prologue: t0 {A0,B0,B1,A1} + t1 {A0,B0}; vmcnt leaves t1's 2 halves in flight
    STAGE_A(0, 0, 0); STAGE_B(0, 0, 0); STAGE_B(0, 1, 0); STAGE_A(0, 1, 0);
    STAGE_A(1, 0, 1); STAGE_B(1, 0, 1);
    vmw<VMN>();
    __builtin_amdgcn_s_barrier();

    for (int kt = 0; kt < NT; ++kt) {
        const int buf = kt & 1, nbuf = buf ^ 1;
        // ph0: quadrant (0,0); stage (kt+1).B1
        LOAD_A(buf, 0); LOAD_B(buf, 0);
        if (kt + 1 < NT) STAGE_B(nbuf, 1, kt + 1);
        SBAR(); LGKM0(); MFMA_Q(0, 0); SBAR();
        // ph1: quadrant (0,1); stage (kt+1).A1
        LOAD_B(buf, 1);
        if (kt + 1 < NT) STAGE_A(nbuf, 1, kt + 1);
        SBAR(); LGKM0(); MFMA_Q(0, 1); SBAR();
        // ph2: quadrant (1,1); stage (kt+2).A0
        LOAD_A(buf, 1);
        if (kt + 2 < NT) STAGE_A(buf, 0, kt + 2);
        SBAR(); LGKM0(); MFMA_Q(1, 1); SBAR();
        // ph3: quadrant (1,0); stage (kt+2).B0; counted vmcnt lands tile kt+1
        if (kt + 2 < NT) STAGE_B(buf, 0, kt + 2);
        SBAR(); LGKM0(); MFMA_Q(1, 0);
        if (kt + 2 < NT)      vmw<VMN>();
        else if (kt + 1 < NT) vmw<0>();
        SBAR();
    }

    // epilogue: C/D layout col = lr, row = 4*g + r
#pragma unroll
    for (int mi = 0; mi < MR; ++mi) {
        const int row0 = m0 + (mi / MQ) * (BM / 2) + wr * (MQ * 16) + (mi % MQ) * 16 + 4 * g;
#pragma unroll
        for (int ni = 0; ni < NR; ++ni) {
            const int col = n0 + (ni / NQ) * (BN / 2) + wc * (NQ * 16) + (ni % NQ) * 16 + lr;
            const float bv = bias[col];
#pragma unroll
            for (int r = 0; r < 4; ++r) {
                float v = acc[mi][ni][r] + bv;
                const size_t idx = (size_t)(row0 + r) * N + col;
                if constexpr (EPI == 1) {
                    ((float*)out)[idx] = v + res[idx];
                } else if constexpr (EPI == 2) {
                    v = 0.5f * v * (1.0f + erff(v * 0.70710678118654752f));
                    ((ushort*)out)[idx] = f2bf(v);
                } else {
                    ((ushort*)out)[idx] = f2bf(v);
                }
            }
        }
    }
#undef STAGE_A
#undef STAGE_B
#undef LOAD_A
#undef LOAD_B
#undef MFMA_Q
#undef ASB
#undef BSB
}

// ---------------------------------------------------------------------------
// Flash attention, swapped-operand 32x32 structure (m214-style):
// grid 1024 blocks (8 qtiles x 128 b*h), 4 waves x 32 q-rows = 128 q/block.
// S^T = mfma32(K, Q): lane holds P[key pattern][q = lane&31] -> softmax fully
// in-register; P -> bf16 via v_cvt_pk feeds PV's B-operand directly.
// O^T = mfma32(V^T, P) so the rescale factor is lane-local.
// ---------------------------------------------------------------------------
__global__ __launch_bounds__(256) void attn_kernel(
    const ushort* __restrict__ qkv, const ushort* __restrict__ vtb,
    ushort* __restrict__ o)
{
    __shared__ __align__(16) ushort Ks[64 * 64];
    __shared__ __align__(16) ushort Vt[64 * 64];

    const int tid = threadIdx.x;
    const int wave = tid >> 6, lane = tid & 63;
    const int lq = lane & 31;
    const int hi = lane >> 5;
    const int l7 = lane & 7;

    const int hwid = blockIdx.x;
    const int logical = (hwid & 7) * 128 + (hwid >> 3);
    const int bh = logical >> 3, qt = logical & 7;
    const int b = bh >> 4, head = bh & 15;
    const int q0 = qt * 128 + wave * 32;

    const size_t base  = (size_t)b * 1024 * 3072;
    const size_t vbase = (size_t)bh * 64 * 1024;

    union BF8 { bf16x8 v; ushort u[8]; unsigned w[4]; };

    BF8 qf[4];
    {
        const ushort* qrow = qkv + base + (size_t)(q0 + lq) * 3072 + head * 64;
#pragma unroll
        for (int s = 0; s < 4; ++s) {
            *(ushort4*)&qf[s].u[0] = *(const ushort4*)(qrow + 16 * s + 4 * hi);
            *(ushort4*)&qf[s].u[4] = *(const ushort4*)(qrow + 16 * s + 8 + 4 * hi);
        }
    }

    const int sr = tid >> 3, sc = tid & 7;
    const int swz = (sc ^ (sr & 7)) << 3;
    const ushort* kg0 = qkv + base + (size_t)sr * 3072 + 1024 + head * 64 + sc * 8;
    const ushort* kg1 = kg0 + (size_t)32 * 3072;
    const ushort* vg0 = vtb + vbase + (size_t)sr * 1024 + sc * 8;
    const ushort* vg1 = vg0 + (size_t)32 * 1024;
    ushort* ksw0 = Ks + sr * 64 + swz;
    ushort* ksw1 = Ks + (sr + 32) * 64 + swz;
    ushort* vsw0 = Vt + sr * 64 + swz;
    ushort* vsw1 = Vt + (sr + 32) * 64 + swz;

    float m_st = -1e30f, l_st = 0.f;
    f32x16 oacc[2] = {};

    constexpr float SCL = 0.18033688011112042f;  // Hd^-0.5 * log2(e)

    for (int kt = 0; kt < 16; ++kt) {
        const int n0 = kt * 64;
        __syncthreads();
        *(bf16x8*)ksw0 = *(const bf16x8*)(kg0 + (size_t)n0 * 3072);
        *(bf16x8*)ksw1 = *(const bf16x8*)(kg1 + (size_t)n0 * 3072);
        *(bf16x8*)vsw0 = *(const bf16x8*)(vg0 + n0);
        *(bf16x8*)vsw1 = *(const bf16x8*)(vg1 + n0);
        __syncthreads();

        f32x16 sacc[2];
#pragma unroll
        for (int kb = 0; kb < 2; ++kb) {
            f32x16 a = {};
            const ushort* krow = Ks + (kb * 32 + lq) * 64;
#pragma unroll
            for (int s = 0; s < 4; ++s) {
                BF8 kf;
                *(ushort4*)&kf.u[0] = *(const ushort4*)(krow + (((2 * s)     ^ l7) << 3) + 4 * hi);
                *(ushort4*)&kf.u[4] = *(const ushort4*)(krow + (((2 * s + 1) ^ l7) << 3) + 4 * hi);
                a = mfma32(kf.v, qf[s].v, a);
            }
            sacc[kb] = a;
        }

        float mloc = -1e30f;
#pragma unroll
        for (int kb = 0; kb < 2; ++kb)
#pragma unroll
            for (int r = 0; r < 16; ++r)
                mloc = fmaxf(mloc, sacc[kb][r]);
        mloc = fmaxf(mloc, __shfl_xor(mloc, 32));
        const float mnew = fmaxf(m_st, mloc * SCL);
        const float resc = exp2f(m_st - mnew);
        m_st = mnew;

        float psum = 0.f;
#pragma unroll
        for (int kb = 0; kb < 2; ++kb)
#pragma unroll
            for (int r = 0; r < 16; ++r) {
                const float pe = exp2f(fmaf(sacc[kb][r], SCL, -mnew));
                sacc[kb][r] = pe;
                psum += pe;
            }
        psum += __shfl_xor(psum, 32);
        l_st = l_st * resc + psum;
#pragma unroll
        for (int nb = 0; nb < 2; ++nb)
#pragma unroll
            for (int r = 0; r < 16; ++r)
                oacc[nb][r] *= resc;

#pragma unroll
        for (int kb = 0; kb < 2; ++kb) {
            BF8 pf[2];
#pragma unroll
            for (int t = 0; t < 2; ++t)
#pragma unroll
                for (int w = 0; w < 4; ++w)
                    pf[t].w[w] = cvtpk(sacc[kb][8 * t + 2 * w], sacc[kb][8 * t + 2 * w + 1]);
#pragma unroll
            for (int nb = 0; nb < 2; ++nb) {
                const ushort* vrow = Vt + (nb * 32 + lq) * 64;
#pragma unroll
                for (int t = 0; t < 2; ++t) {
                    BF8 vf;
                    const int blk = 4 * kb + 2 * t;
                    *(ushort4*)&vf.u[0] = *(const ushort4*)(vrow + ((blk       ^ l7) << 3) + 4 * hi);
                    *(ushort4*)&vf.u[4] = *(const ushort4*)(vrow + (((blk + 1) ^ l7) << 3) + 4 * hi);
                    oacc[nb] = mfma32(vf.v, pf[t].v, oacc[nb]);
                }
            }
        }
    }

    const float inv = 1.0f / l_st;
    ushort* orow = o + (size_t)(b * 1024 + q0 + lq) * 1024 + head * 64;
#pragma unroll
    for (int nb = 0; nb < 2; ++nb)
#pragma unroll
        for (int u = 0; u < 4; ++u) {
            uint2 wv;
            wv.x = cvtpk(oacc[nb][4 * u] * inv,     oacc[nb][4 * u + 1] * inv);
            wv.y = cvtpk(oacc[nb][4 * u + 2] * inv, oacc[nb][4 * u + 3] * inv);
            *(uint2*)(orow + nb * 32 + 8 * u + 4 * hi) = wv;
        }
}

// ---------------------------------------------------------------------------
extern "C" void kernel_launch(void* const* d_in, const int* in_sizes, int n_in,
                              void* d_out, int out_size, void* d_ws, size_t ws_size,
                              hipStream_t stream)
{
    const float* x      = (const float*)d_in[0];
    const float* qkv_w  = (const float*)d_in[1];
    const float* qkv_b  = (const float*)d_in[2];
    const float* out_w  = (const float*)d_in[3];
    const float* out_b  = (const float*)d_in[4];
    const float* ffn_w1 = (const float*)d_in[5];
    const float* ffn_b1 = (const float*)d_in[6];
    const float* ffn_w2 = (const float*)d_in[7];
    const float* ffn_b2 = (const float*)d_in[8];
    const float* ln1_g  = (const float*)d_in[9];
    const float* ln1_b  = (const float*)d_in[10];
    const float* ln2_g  = (const float*)d_in[11];
    const float* ln2_b  = (const float*)d_in[12];

    constexpr size_t MB = 1u << 20;
    char* ws = (char*)d_ws;
    ushort* wt_qkv = (ushort*)(ws + 0 * MB);     // [3072][1024] bf16  (6 MB)
    ushort* wt_out = (ushort*)(ws + 6 * MB);     // [1024][1024]       (2 MB)
    ushort* wt_f1  = (ushort*)(ws + 8 * MB);     // [4096][1024]       (8 MB)
    ushort* wt_f2  = (ushort*)(ws + 16 * MB);    // [1024][4096]       (8 MB)
    float*  x1     = (float*) (ws + 24 * MB);    // [8192][1024] f32   (32 MB)
    ushort* vtb    = (ushort*)(ws + 24 * MB);    // [128][64][1024]    (16 MB, aliases x1)
    ushort* hbuf   = (ushort*)(ws + 56 * MB);    // [8192][1024] bf16  (16 MB)
    ushort* qkvb   = (ushort*)(ws + 72 * MB);    // [8192][3072] bf16  (48 MB)
    ushort* obuf   = (ushort*)(ws + 120 * MB);   // [8192][1024] bf16  (16 MB)
    ushort* gbuf   = (ushort*)(ws + 72 * MB);    // [8192][4096] bf16  (64 MB, aliases qkvb+obuf)

    const dim3 tb(32, 8);
    transpose_w<<<dim3(3072 / 32, 1024 / 32), tb, 0, stream>>>(qkv_w,  wt_qkv, 1024, 3072);
    transpose_w<<<dim3(1024 / 32, 1024 / 32), tb, 0, stream>>>(out_w,  wt_out, 1024, 1024);
    transpose_w<<<dim3(4096 / 32, 1024 / 32), tb, 0, stream>>>(ffn_w1, wt_f1,  1024, 4096);
    transpose_w<<<dim3(1024 / 32, 4096 / 32), tb, 0, stream>>>(ffn_w2, wt_f2,  4096, 1024);

    ln_bf16<<<8192, 256, 0, stream>>>(x, ln1_g, ln1_b, hbuf);

    constexpr int LDS_256 = (256 * 64 * 2 + 256 * 64 * 2) * 2;  // 128 KiB
    constexpr int LDS_128 = (256 * 64 * 2 + 128 * 64 * 2) * 2;  //  96 KiB

    gemm8p<256, 256, 2, 4, 0><<<dim3(12, 32), 512, LDS_256, stream>>>(
        hbuf, wt_qkv, qkv_b, nullptr, qkvb, 8192, 3072, 1024);

    transpose_v<<<dim3(32, 2, 128), tb, 0, stream>>>(qkvb, vtb);

    attn_kernel<<<1024, 256, 0, stream>>>(qkvb, vtb, obuf);

    gemm8p<256, 128, 4, 2, 1><<<dim3(8, 32), 512, LDS_128, stream>>>(
        obuf, wt_out, out_b, x, x1, 8192, 1024, 1024);

    ln_bf16<<<8192, 256, 0, stream>>>(x1, ln2_g, ln2_b, hbuf);

    gemm8p<256, 256, 2, 4, 2><<<dim3(16, 32), 512, LDS_256, stream>>>(
        hbuf, wt_f1, ffn_b1, nullptr, gbuf, 8192, 4096, 1024);

    gemm8p<256, 128, 4, 2, 1><<<dim3(8, 32), 512, LDS_128, stream>>>(
        gbuf, wt_f2, ffn_b2, x1, (float*)d_out, 8192, 1024, 4096);
}